// Round 5
// baseline (189.017 us; speedup 1.0000x reference)
//
#include <hip/hip_runtime.h>
#include <hip/hip_bf16.h>
#include <cstdint>

#define BB 2
#define SS 2048
#define DD 1024
#define HH 16
#define DK 64
#define MROWS (BB*SS)        // 4096
#define NQKV  (3*DD)         // 3072

typedef __bf16 bf16x8 __attribute__((ext_vector_type(8)));
typedef float  f32x4  __attribute__((ext_vector_type(4)));

static __device__ __forceinline__ unsigned short f2bf(float f) {
    __bf16 h = (__bf16)f;
    return __builtin_bit_cast(unsigned short, h);
}
static __device__ __forceinline__ float bf2f(unsigned short u) {
    return (float)__builtin_bit_cast(__bf16, u);
}

#define GLOAD16(gsrc, ldst) \
    __builtin_amdgcn_global_load_lds((const __attribute__((address_space(1))) void*)(gsrc), \
                                     (__attribute__((address_space(3))) void*)(ldst), 16, 0, 0)

// ---------------------------------------------------------------- cast x + weights to bf16
__global__ void cast_all(const float* __restrict__ x,  const float* __restrict__ wq,
                         const float* __restrict__ wk, const float* __restrict__ wv,
                         const float* __restrict__ wo,
                         unsigned short* __restrict__ xb, unsigned short* __restrict__ wqkv,
                         unsigned short* __restrict__ wob)
{
    const int NX = MROWS * DD;      // 4194304
    const int NW = DD * DD;         // 1048576
    const int total = (NX + 4 * NW) / 8;
    for (int i = blockIdx.x * blockDim.x + threadIdx.x; i < total; i += gridDim.x * blockDim.x) {
        int base = i * 8;
        const float* src; unsigned short* dst; int off;
        if      (base < NX)          { src = x;  dst = xb;          off = base; }
        else if (base < NX + NW)     { src = wq; dst = wqkv;        off = base - NX; }
        else if (base < NX + 2*NW)   { src = wk; dst = wqkv + NW;   off = base - NX - NW; }
        else if (base < NX + 3*NW)   { src = wv; dst = wqkv + 2*NW; off = base - NX - 2*NW; }
        else                         { src = wo; dst = wob;         off = base - NX - 3*NW; }
        float4 a = *(const float4*)(src + off);
        float4 b = *(const float4*)(src + off + 4);
        union { unsigned short s[8]; uint4 v; } u;
        u.s[0] = f2bf(a.x); u.s[1] = f2bf(a.y); u.s[2] = f2bf(a.z); u.s[3] = f2bf(a.w);
        u.s[4] = f2bf(b.x); u.s[5] = f2bf(b.y); u.s[6] = f2bf(b.z); u.s[7] = f2bf(b.w);
        *(uint4*)(dst + off) = u.v;
    }
}

// ---------------------------------------------------------------- RoPE cos/sin table [2048][32]
__global__ void rope_table(float* __restrict__ tabc, float* __restrict__ tabs)
{
    int i = blockIdx.x * blockDim.x + threadIdx.x;   // 65536 threads
    int s = i >> 5, d = i & 31;
    float inv = exp2f(-(float)d * (13.287712379549449f / 32.f));  // 10000^(-d/32)
    float ang = (float)s * inv;
    tabc[i] = cosf(ang);
    tabs[i] = sinf(ang);
}

// ---------------------------------------------------------------- GEMM  C[M][N] = A[M][K] * B[N][K]^T
// 128x128 tile, BK=64, 4 waves (2x2), 16x16x32 bf16 MFMA, global_load_lds staging.
template<int OUTF32>
__global__ __launch_bounds__(256) void gemm_bt(
    const unsigned short* __restrict__ A, const unsigned short* __restrict__ Bm,
    void* __restrict__ Cout, const float* __restrict__ bias,
    int M, int N, int K)
{
    __shared__ __align__(16) unsigned short sA[128 * 64];
    __shared__ __align__(16) unsigned short sB[128 * 64];
    const int tid = threadIdx.x;
    const int w = tid >> 6, l = tid & 63;
    const int wm = w >> 1, wn = w & 1;
    const int lr = l & 15, lg = l >> 4;
    const int mBase = blockIdx.y * 128, nBase = blockIdx.x * 128;
    const int srow = tid >> 3;           // 0..31
    const int skof = (tid & 7) * 8;      // element offset in K

    f32x4 acc[4][4] = {};

    for (int kt = 0; kt < K; kt += 64) {
        __syncthreads();
        #pragma unroll
        for (int i = 0; i < 4; ++i) {
            const unsigned short* srcA = A + (size_t)(mBase + i*32 + srow) * K + kt + skof;
            GLOAD16(srcA, &sA[i*2048 + w*512]);
            const unsigned short* srcB = Bm + (size_t)(nBase + i*32 + srow) * K + kt + skof;
            GLOAD16(srcB, &sB[i*2048 + w*512]);
        }
        __syncthreads();
        #pragma unroll
        for (int kk = 0; kk < 2; ++kk) {
            bf16x8 af[4], bfv[4];
            #pragma unroll
            for (int mi = 0; mi < 4; ++mi)
                af[mi] = *(const bf16x8*)&sA[(wm*64 + mi*16 + lr)*64 + kk*32 + lg*8];
            #pragma unroll
            for (int ni = 0; ni < 4; ++ni)
                bfv[ni] = *(const bf16x8*)&sB[(wn*64 + ni*16 + lr)*64 + kk*32 + lg*8];
            #pragma unroll
            for (int mi = 0; mi < 4; ++mi)
                #pragma unroll
                for (int ni = 0; ni < 4; ++ni)
                    acc[mi][ni] = __builtin_amdgcn_mfma_f32_16x16x32_bf16(af[mi], bfv[ni], acc[mi][ni], 0, 0, 0);
        }
    }
    #pragma unroll
    for (int mi = 0; mi < 4; ++mi) {
        #pragma unroll
        for (int j = 0; j < 4; ++j) {
            int row = mBase + wm*64 + mi*16 + lg*4 + j;
            #pragma unroll
            for (int ni = 0; ni < 4; ++ni) {
                int col = nBase + wn*64 + ni*16 + lr;
                float v = acc[mi][ni][j];
                if (OUTF32) ((float*)Cout)[(size_t)row * N + col] = v + bias[col];
                else        ((unsigned short*)Cout)[(size_t)row * N + col] = f2bf(v);
            }
        }
    }
}

// ---------------------------------------------------------------- RoPE on Q,K (vectorized)
// Q pre-scaled by (1/sqrt(dk)) * log2(e) so attention works in the exp2 domain.
__global__ void rope_qk(const unsigned short* __restrict__ qkv,
                        const int* __restrict__ pids,
                        const float* __restrict__ tabc, const float* __restrict__ tabs,
                        unsigned short* __restrict__ Qb, unsigned short* __restrict__ Kb)
{
    int i = blockIdx.x * blockDim.x + threadIdx.x;   // 524288 threads
    int cb = i & 3;
    int h  = (i >> 2) & 15;
    int isK = (i >> 6) & 1;
    int r  = i >> 7;
    int pos = pids[r];
    int dbase = cb * 8;

    const unsigned short* src = qkv + (size_t)r * NQKV + isK * DD + h * 64 + dbase;
    union { unsigned short u[8]; uint4 v; } a, bq, o1, o2;
    a.v  = *(const uint4*)src;
    bq.v = *(const uint4*)(src + 32);
    float cs[8], sn[8];
    *(float4*)&cs[0] = *(const float4*)(tabc + pos*32 + dbase);
    *(float4*)&cs[4] = *(const float4*)(tabc + pos*32 + dbase + 4);
    *(float4*)&sn[0] = *(const float4*)(tabs + pos*32 + dbase);
    *(float4*)&sn[4] = *(const float4*)(tabs + pos*32 + dbase + 4);
    float scale = isK ? 1.0f : 0.1803368801111244f;   // 0.125 * log2(e)
    #pragma unroll
    for (int j = 0; j < 8; ++j) {
        float v1 = bf2f(a.u[j]), v2 = bf2f(bq.u[j]);
        o1.u[j] = f2bf((v1*cs[j] - v2*sn[j]) * scale);
        o2.u[j] = f2bf((v2*cs[j] + v1*sn[j]) * scale);
    }
    unsigned short* dst = (isK ? Kb : Qb) + (size_t)r * DD + h * 64 + dbase;
    *(uint4*)dst        = o1.v;
    *(uint4*)(dst + 32) = o2.v;
}

// ---------------------------------------------------------------- V transpose via chunk-swizzled LDS tile
// qkv [4096][3072] (V at col 2048) -> Vt [32*64][2048]
__global__ __launch_bounds__(256) void v_transpose(
    const unsigned short* __restrict__ qkv, unsigned short* __restrict__ Vt)
{
    __shared__ __align__(16) unsigned short sT[64 * 64];
    const int bh = blockIdx.y;          // 0..31
    const int st = blockIdx.x;          // 0..31 (s-tile)
    const int b = bh >> 4, h = bh & 15;
    const int tid = threadIdx.x;
    #pragma unroll
    for (int i = 0; i < 2; ++i) {
        int c = tid + i*256;            // chunk 0..511
        int s = c >> 3, cb = c & 7;
        const unsigned short* src = qkv + (size_t)(b*SS + st*64 + s) * NQKV + 2*DD + h*64 + cb*8;
        uint4 v = *(const uint4*)src;
        *(uint4*)&sT[s*64 + ((cb ^ (s >> 3)) * 8)] = v;   // chunk-swizzled store
    }
    __syncthreads();
    #pragma unroll
    for (int i = 0; i < 2; ++i) {
        int c = tid + i*256;
        int d = c >> 3, sb = c & 7;
        union { unsigned short u[8]; uint4 v; } o;
        #pragma unroll
        for (int e = 0; e < 8; ++e) {
            int s = sb*8 + e;
            o.u[e] = sT[s*64 + (((d >> 3) ^ (s >> 3)) * 8) + (d & 7)];
        }
        *(uint4*)(Vt + (size_t)(bh*64 + d) * SS + st*64 + sb*8) = o.v;
    }
}

// ---------------------------------------------------------------- flash attention fwd (causal)
// 1024 blocks (one 64-row q-tile each), XCD-chunk swizzled (4 bh per XCD -> 2MB K/V chunk in L2).
// Double-buffered K/V staging: 1 barrier per kv-step, next tile's global_load_lds issued
// before compute so HBM/L2 latency hides under QK+softmax+PV. exp2 softmax + defer-max.
__global__ __launch_bounds__(256) void attn_fwd(
    const unsigned short* __restrict__ Qb,   // [4096][1024], pre-scaled by 0.125*log2e
    const unsigned short* __restrict__ Kb,   // [4096][1024]
    const unsigned short* __restrict__ Vt,   // [2048][2048]
    unsigned short* __restrict__ Ob)         // [4096][1024]
{
    __shared__ __align__(16) unsigned short sK[2][64 * 64];
    __shared__ __align__(16) unsigned short sV[2][64 * 64];
    __shared__ __align__(16) unsigned short sP[4][16 * 64];
    const int tid = threadIdx.x;
    const int w = tid >> 6, l = tid & 63;
    const int lr = l & 15, lg = l >> 4;
    // XCD-chunked swizzle: 1024 blocks = 8 XCDs x 128; each XCD owns 4 consecutive bh.
    const int swz = (blockIdx.x & 7) * 128 + (blockIdx.x >> 3);
    const int qt = swz & 31;                 // q-tile 0..31
    const int bh = swz >> 5;                 // 0..31
    const int b = bh >> 4, h = bh & 15;
    const int srow = tid >> 3;
    const int skof = (tid & 7) * 8;
    const int sksw = skof ^ ((srow & 7) * 8);   // pre-swizzled staging col (elements)
    const int rdsw = (lr & 7) * 8;              // read-side XOR term
    const float THR = 12.0f;                    // defer-max threshold (log2 units)

    const int q0 = qt*64 + w*16;
    bf16x8 qf[2];
    {
        const unsigned short* qp = Qb + (size_t)(b*SS + q0 + lr) * DD + h*64 + lg*8;
        qf[0] = *(const bf16x8*)qp;
        qf[1] = *(const bf16x8*)(qp + 32);
    }
    f32x4 oacc[4] = {};
    float mrow[4], lsum[4];
    #pragma unroll
    for (int j = 0; j < 4; ++j) { mrow[j] = -3.0e38f; lsum[j] = 0.f; }

    // prologue: stage tile 0 into buffer 0
    #pragma unroll
    for (int i = 0; i < 2; ++i) {
        const unsigned short* srcK = Kb + (size_t)(b*SS + i*32 + srow) * DD + h*64 + sksw;
        GLOAD16(srcK, &sK[0][i*2048 + w*512]);
        const unsigned short* srcV = Vt + (size_t)(bh*64 + i*32 + srow) * SS + sksw;
        GLOAD16(srcV, &sV[0][i*2048 + w*512]);
    }
    int cur = 0;

    for (int kt = 0; kt <= qt; ++kt) {
        __syncthreads();   // compiler drains vmcnt before s_barrier: buf[cur] is staged,
                           // and all waves finished reading buf[cur^1] last iteration.
        if (kt < qt) {
            #pragma unroll
            for (int i = 0; i < 2; ++i) {
                const unsigned short* srcK = Kb + (size_t)(b*SS + (kt+1)*64 + i*32 + srow) * DD + h*64 + sksw;
                GLOAD16(srcK, &sK[cur^1][i*2048 + w*512]);
                const unsigned short* srcV = Vt + (size_t)(bh*64 + i*32 + srow) * SS + (kt+1)*64 + sksw;
                GLOAD16(srcV, &sV[cur^1][i*2048 + w*512]);
            }
        }

        f32x4 sacc[4] = {};
        __builtin_amdgcn_s_setprio(1);
        #pragma unroll
        for (int kk = 0; kk < 2; ++kk) {
            #pragma unroll
            for (int ni = 0; ni < 4; ++ni) {
                bf16x8 kf = *(const bf16x8*)&sK[cur][(ni*16 + lr)*64 + ((kk*32 + lg*8) ^ rdsw)];
                sacc[ni] = __builtin_amdgcn_mfma_f32_16x16x32_bf16(qf[kk], kf, sacc[ni], 0, 0, 0);
            }
        }
        __builtin_amdgcn_s_setprio(0);
        const bool diag = (kt == qt);
        float tmx[4];
        #pragma unroll
        for (int j = 0; j < 4; ++j) {
            int qrow = q0 + lg*4 + j;
            float mx = -3.0e38f;
            #pragma unroll
            for (int ni = 0; ni < 4; ++ni) {
                float v = sacc[ni][j];
                if (diag) {
                    int kcol = kt*64 + ni*16 + lr;
                    if (kcol > qrow) v = -1e30f;
                }
                sacc[ni][j] = v;
                mx = fmaxf(mx, v);
            }
            mx = fmaxf(mx, __shfl_xor(mx, 1));
            mx = fmaxf(mx, __shfl_xor(mx, 2));
            mx = fmaxf(mx, __shfl_xor(mx, 4));
            mx = fmaxf(mx, __shfl_xor(mx, 8));
            tmx[j] = mx;
        }
        // T13 defer-max: rescale only if some row grew by more than THR
        float growth = tmx[0] - mrow[0];
        #pragma unroll
        for (int j = 1; j < 4; ++j) growth = fmaxf(growth, tmx[j] - mrow[j]);
        if (!__all(growth <= THR)) {
            #pragma unroll
            for (int j = 0; j < 4; ++j) {
                float mnew = fmaxf(mrow[j], tmx[j]);
                float alpha = exp2f(mrow[j] - mnew);
                lsum[j] *= alpha;
                mrow[j] = mnew;
                #pragma unroll
                for (int di = 0; di < 4; ++di) oacc[di][j] *= alpha;
            }
        }
        #pragma unroll
        for (int j = 0; j < 4; ++j) {
            float rs = 0.f;
            #pragma unroll
            for (int ni = 0; ni < 4; ++ni) {
                float p = exp2f(sacc[ni][j] - mrow[j]);
                sacc[ni][j] = p;
                rs += p;
            }
            rs += __shfl_xor(rs, 1);
            rs += __shfl_xor(rs, 2);
            rs += __shfl_xor(rs, 4);
            rs += __shfl_xor(rs, 8);
            lsum[j] += rs;
        }
        // P -> LDS (bf16), swizzled both sides (per-wave buffer, no block barrier needed)
        #pragma unroll
        for (int j = 0; j < 4; ++j) {
            int rp = lg*4 + j;
            #pragma unroll
            for (int ni = 0; ni < 4; ++ni)
                sP[w][rp*64 + ((ni*16 + lr) ^ ((rp & 7)*8))] = f2bf(sacc[ni][j]);
        }
        asm volatile("s_waitcnt lgkmcnt(0)" ::: "memory");
        __builtin_amdgcn_sched_barrier(0);
        __builtin_amdgcn_s_setprio(1);
        #pragma unroll
        for (int kk = 0; kk < 2; ++kk) {
            bf16x8 pf = *(const bf16x8*)&sP[w][lr*64 + ((kk*32 + lg*8) ^ rdsw)];
            #pragma unroll
            for (int di = 0; di < 4; ++di) {
                bf16x8 vf = *(const bf16x8*)&sV[cur][(di*16 + lr)*64 + ((kk*32 + lg*8) ^ rdsw)];
                oacc[di] = __builtin_amdgcn_mfma_f32_16x16x32_bf16(pf, vf, oacc[di], 0, 0, 0);
            }
        }
        __builtin_amdgcn_s_setprio(0);
        cur ^= 1;
    }
    #pragma unroll
    for (int j = 0; j < 4; ++j) {
        float inv = 1.f / lsum[j];
        size_t row = (size_t)(b*SS + q0 + lg*4 + j);
        #pragma unroll
        for (int di = 0; di < 4; ++di)
            Ob[row * DD + h*64 + di*16 + lr] = f2bf(oacc[di][j] * inv);
    }
}

// ---------------------------------------------------------------- launch
extern "C" void kernel_launch(void* const* d_in, const int* in_sizes, int n_in,
                              void* d_out, int out_size, void* d_ws, size_t ws_size,
                              hipStream_t stream)
{
    const float* x  = (const float*)d_in[0];
    // d_in[1] = mask (causal tril; implemented analytically)
    const int* pids = (const int*)d_in[2];
    const float* wq = (const float*)d_in[3];
    const float* wk = (const float*)d_in[4];
    const float* wv = (const float*)d_in[5];
    const float* wo = (const float*)d_in[6];
    const float* bo = (const float*)d_in[7];
    float* out = (float*)d_out;

    char* ws = (char*)d_ws;
    unsigned short* xb   = (unsigned short*)(ws);                        // 8 MB
    unsigned short* wqkv = (unsigned short*)(ws + (size_t)( 8u<<20));    // 6 MB
    unsigned short* wob  = (unsigned short*)(ws + (size_t)(14u<<20));    // 2 MB
    unsigned short* qkvp = (unsigned short*)(ws + (size_t)(16u<<20));    // 24 MB
    unsigned short* Qb   = (unsigned short*)(ws + (size_t)(40u<<20));    // 8 MB
    unsigned short* Kb   = (unsigned short*)(ws + (size_t)(48u<<20));    // 8 MB
    unsigned short* Vt   = (unsigned short*)(ws + (size_t)(56u<<20));    // 8 MB
    float* tabc          = (float*)(ws + (size_t)(64u<<20));             // 256 KB
    float* tabs          = (float*)(ws + (size_t)(64u<<20) + (256u<<10));// 256 KB
    unsigned short* Ob   = xb;  // alias: x_bf16 dead after QKV GEMM

    cast_all<<<dim3(4096), dim3(256), 0, stream>>>(x, wq, wk, wv, wo, xb, wqkv, wob);
    rope_table<<<dim3(256), dim3(256), 0, stream>>>(tabc, tabs);
    gemm_bt<0><<<dim3(NQKV/128, MROWS/128), dim3(256), 0, stream>>>(
        xb, wqkv, (void*)qkvp, (const float*)nullptr, MROWS, NQKV, DD);
    rope_qk<<<dim3(2048), dim3(256), 0, stream>>>(qkvp, pids, tabc, tabs, Qb, Kb);
    v_transpose<<<dim3(32, 32), dim3(256), 0, stream>>>(qkvp, Vt);
    attn_fwd<<<dim3(1024), dim3(256), 0, stream>>>(Qb, Kb, Vt, Ob);
    gemm_bt<1><<<dim3(DD/128, MROWS/128), dim3(256), 0, stream>>>(
        Ob, wob, (void*)out, bo, MROWS, DD, DD);
}

// Round 7
// 171.112 us; speedup vs baseline: 1.1046x; 1.1046x over previous
//
#include <hip/hip_runtime.h>
#include <hip/hip_bf16.h>
#include <cstdint>

#define BB 2
#define SS 2048
#define DD 1024
#define HH 16
#define DK 64
#define MROWS (BB*SS)        // 4096
#define NQKV  (3*DD)         // 3072

typedef __bf16 bf16x8 __attribute__((ext_vector_type(8)));
typedef float  f32x4  __attribute__((ext_vector_type(4)));

static __device__ __forceinline__ unsigned short f2bf(float f) {
    __bf16 h = (__bf16)f;
    return __builtin_bit_cast(unsigned short, h);
}
static __device__ __forceinline__ float bf2f(unsigned short u) {
    return (float)__builtin_bit_cast(__bf16, u);
}

#define GLOAD16(gsrc, ldst) \
    __builtin_amdgcn_global_load_lds((const __attribute__((address_space(1))) void*)(gsrc), \
                                     (__attribute__((address_space(3))) void*)(ldst), 16, 0, 0)

// ---------------------------------------------------------------- cast x + weights to bf16
__global__ void cast_all(const float* __restrict__ x,  const float* __restrict__ wq,
                         const float* __restrict__ wk, const float* __restrict__ wv,
                         const float* __restrict__ wo,
                         unsigned short* __restrict__ xb, unsigned short* __restrict__ wqkv,
                         unsigned short* __restrict__ wob)
{
    const int NX = MROWS * DD;      // 4194304
    const int NW = DD * DD;         // 1048576
    const int total = (NX + 4 * NW) / 8;
    for (int i = blockIdx.x * blockDim.x + threadIdx.x; i < total; i += gridDim.x * blockDim.x) {
        int base = i * 8;
        const float* src; unsigned short* dst; int off;
        if      (base < NX)          { src = x;  dst = xb;          off = base; }
        else if (base < NX + NW)     { src = wq; dst = wqkv;        off = base - NX; }
        else if (base < NX + 2*NW)   { src = wk; dst = wqkv + NW;   off = base - NX - NW; }
        else if (base < NX + 3*NW)   { src = wv; dst = wqkv + 2*NW; off = base - NX - 2*NW; }
        else                         { src = wo; dst = wob;         off = base - NX - 3*NW; }
        float4 a = *(const float4*)(src + off);
        float4 b = *(const float4*)(src + off + 4);
        union { unsigned short s[8]; uint4 v; } u;
        u.s[0] = f2bf(a.x); u.s[1] = f2bf(a.y); u.s[2] = f2bf(a.z); u.s[3] = f2bf(a.w);
        u.s[4] = f2bf(b.x); u.s[5] = f2bf(b.y); u.s[6] = f2bf(b.z); u.s[7] = f2bf(b.w);
        *(uint4*)(dst + off) = u.v;
    }
}

// ---------------------------------------------------------------- RoPE cos/sin table [2048][32]
__global__ void rope_table(float* __restrict__ tabc, float* __restrict__ tabs)
{
    int i = blockIdx.x * blockDim.x + threadIdx.x;   // 65536 threads
    int s = i >> 5, d = i & 31;
    float inv = exp2f(-(float)d * (13.287712379549449f / 32.f));  // 10000^(-d/32)
    float ang = (float)s * inv;
    tabc[i] = cosf(ang);
    tabs[i] = sinf(ang);
}

// ---------------------------------------------------------------- GEMM  C[M][N] = A[M][K] * B[N][K]^T
// 128x128 tile, BK=64, 4 waves (2x2), 16x16x32 bf16 MFMA, global_load_lds staging.
template<int OUTF32>
__global__ __launch_bounds__(256) void gemm_bt(
    const unsigned short* __restrict__ A, const unsigned short* __restrict__ Bm,
    void* __restrict__ Cout, const float* __restrict__ bias,
    int M, int N, int K)
{
    __shared__ __align__(16) unsigned short sA[128 * 64];
    __shared__ __align__(16) unsigned short sB[128 * 64];
    const int tid = threadIdx.x;
    const int w = tid >> 6, l = tid & 63;
    const int wm = w >> 1, wn = w & 1;
    const int lr = l & 15, lg = l >> 4;
    const int mBase = blockIdx.y * 128, nBase = blockIdx.x * 128;
    const int srow = tid >> 3;           // 0..31
    const int skof = (tid & 7) * 8;      // element offset in K

    f32x4 acc[4][4] = {};

    for (int kt = 0; kt < K; kt += 64) {
        __syncthreads();
        #pragma unroll
        for (int i = 0; i < 4; ++i) {
            const unsigned short* srcA = A + (size_t)(mBase + i*32 + srow) * K + kt + skof;
            GLOAD16(srcA, &sA[i*2048 + w*512]);
            const unsigned short* srcB = Bm + (size_t)(nBase + i*32 + srow) * K + kt + skof;
            GLOAD16(srcB, &sB[i*2048 + w*512]);
        }
        __syncthreads();
        #pragma unroll
        for (int kk = 0; kk < 2; ++kk) {
            bf16x8 af[4], bfv[4];
            #pragma unroll
            for (int mi = 0; mi < 4; ++mi)
                af[mi] = *(const bf16x8*)&sA[(wm*64 + mi*16 + lr)*64 + kk*32 + lg*8];
            #pragma unroll
            for (int ni = 0; ni < 4; ++ni)
                bfv[ni] = *(const bf16x8*)&sB[(wn*64 + ni*16 + lr)*64 + kk*32 + lg*8];
            #pragma unroll
            for (int mi = 0; mi < 4; ++mi)
                #pragma unroll
                for (int ni = 0; ni < 4; ++ni)
                    acc[mi][ni] = __builtin_amdgcn_mfma_f32_16x16x32_bf16(af[mi], bfv[ni], acc[mi][ni], 0, 0, 0);
        }
    }
    #pragma unroll
    for (int mi = 0; mi < 4; ++mi) {
        #pragma unroll
        for (int j = 0; j < 4; ++j) {
            int row = mBase + wm*64 + mi*16 + lg*4 + j;
            #pragma unroll
            for (int ni = 0; ni < 4; ++ni) {
                int col = nBase + wn*64 + ni*16 + lr;
                float v = acc[mi][ni][j];
                if (OUTF32) ((float*)Cout)[(size_t)row * N + col] = v + bias[col];
                else        ((unsigned short*)Cout)[(size_t)row * N + col] = f2bf(v);
            }
        }
    }
}

// ---------------------------------------------------------------- RoPE on Q,K (vectorized)
// Q pre-scaled by (1/sqrt(dk)) * log2(e) so attention works in the exp2 domain.
__global__ void rope_qk(const unsigned short* __restrict__ qkv,
                        const int* __restrict__ pids,
                        const float* __restrict__ tabc, const float* __restrict__ tabs,
                        unsigned short* __restrict__ Qb, unsigned short* __restrict__ Kb)
{
    int i = blockIdx.x * blockDim.x + threadIdx.x;   // 524288 threads
    int cb = i & 3;
    int h  = (i >> 2) & 15;
    int isK = (i >> 6) & 1;
    int r  = i >> 7;
    int pos = pids[r];
    int dbase = cb * 8;

    const unsigned short* src = qkv + (size_t)r * NQKV + isK * DD + h * 64 + dbase;
    union { unsigned short u[8]; uint4 v; } a, bq, o1, o2;
    a.v  = *(const uint4*)src;
    bq.v = *(const uint4*)(src + 32);
    float cs[8], sn[8];
    *(float4*)&cs[0] = *(const float4*)(tabc + pos*32 + dbase);
    *(float4*)&cs[4] = *(const float4*)(tabc + pos*32 + dbase + 4);
    *(float4*)&sn[0] = *(const float4*)(tabs + pos*32 + dbase);
    *(float4*)&sn[4] = *(const float4*)(tabs + pos*32 + dbase + 4);
    float scale = isK ? 1.0f : 0.1803368801111244f;   // 0.125 * log2(e)
    #pragma unroll
    for (int j = 0; j < 8; ++j) {
        float v1 = bf2f(a.u[j]), v2 = bf2f(bq.u[j]);
        o1.u[j] = f2bf((v1*cs[j] - v2*sn[j]) * scale);
        o2.u[j] = f2bf((v2*cs[j] + v1*sn[j]) * scale);
    }
    unsigned short* dst = (isK ? Kb : Qb) + (size_t)r * DD + h * 64 + dbase;
    *(uint4*)dst        = o1.v;
    *(uint4*)(dst + 32) = o2.v;
}

// ---------------------------------------------------------------- V transpose via chunk-swizzled LDS tile
// qkv [4096][3072] (V at col 2048) -> Vt [32*64][2048]
__global__ __launch_bounds__(256) void v_transpose(
    const unsigned short* __restrict__ qkv, unsigned short* __restrict__ Vt)
{
    __shared__ __align__(16) unsigned short sT[64 * 64];
    const int bh = blockIdx.y;          // 0..31
    const int st = blockIdx.x;          // 0..31 (s-tile)
    const int b = bh >> 4, h = bh & 15;
    const int tid = threadIdx.x;
    #pragma unroll
    for (int i = 0; i < 2; ++i) {
        int c = tid + i*256;            // chunk 0..511
        int s = c >> 3, cb = c & 7;
        const unsigned short* src = qkv + (size_t)(b*SS + st*64 + s) * NQKV + 2*DD + h*64 + cb*8;
        uint4 v = *(const uint4*)src;
        *(uint4*)&sT[s*64 + ((cb ^ (s >> 3)) * 8)] = v;   // chunk-swizzled store
    }
    __syncthreads();
    #pragma unroll
    for (int i = 0; i < 2; ++i) {
        int c = tid + i*256;
        int d = c >> 3, sb = c & 7;
        union { unsigned short u[8]; uint4 v; } o;
        #pragma unroll
        for (int e = 0; e < 8; ++e) {
            int s = sb*8 + e;
            o.u[e] = sT[s*64 + (((d >> 3) ^ (s >> 3)) * 8) + (d & 7)];
        }
        *(uint4*)(Vt + (size_t)(bh*64 + d) * SS + st*64 + sb*8) = o.v;
    }
}

// ---------------------------------------------------------------- flash attention fwd (causal)
// 512 blocks, XCD-chunk swizzled. Block handles q-tiles {pair, 31-pair} as ONE fused
// 33-step kv sequence (balanced, placement-immune) with double-buffered K/V staging:
// one __syncthreads per step; next tile's global_load_lds issued right after it so the
// stage latency hides under QK+softmax+PV of the current tile. exp2 softmax, defer-max,
// deferred cross-lane sum (lsum reduced once per half instead of every step).
__global__ __launch_bounds__(256) void attn_fwd(
    const unsigned short* __restrict__ Qb,   // [4096][1024], pre-scaled by 0.125*log2e
    const unsigned short* __restrict__ Kb,   // [4096][1024]
    const unsigned short* __restrict__ Vt,   // [2048][2048]
    unsigned short* __restrict__ Ob)         // [4096][1024]
{
    __shared__ __align__(16) unsigned short sK[2][64 * 64];
    __shared__ __align__(16) unsigned short sV[2][64 * 64];
    __shared__ __align__(16) unsigned short sP[4][16 * 64];
    const int tid = threadIdx.x;
    const int w = tid >> 6, l = tid & 63;
    const int lr = l & 15, lg = l >> 4;
    // XCD-chunked swizzle: 512 blocks = 8 XCDs x 64; each XCD owns 4 consecutive bh.
    const int swz = (blockIdx.x & 7) * 64 + (blockIdx.x >> 3);
    const int pair = swz & 15;               // 0..15
    const int bh = swz >> 4;                 // 0..31
    const int b = bh >> 4, h = bh & 15;
    const int srow = tid >> 3;
    const int skof = (tid & 7) * 8;
    const int sksw = skof ^ ((srow & 7) * 8);   // pre-swizzled staging col (elements)
    const int rdsw = (lr & 7) * 8;              // read-side XOR term
    const float THR = 12.0f;                    // defer-max threshold (log2 units)

    const int qt1 = pair, qt2 = 31 - pair;
    const int steps1 = qt1 + 1;
    const int total = qt1 + qt2 + 2;            // 33

    // Q fragments for both halves, loaded once
    bf16x8 qa1[2], qa2[2];
    {
        const unsigned short* qp1 = Qb + (size_t)(b*SS + qt1*64 + w*16 + lr) * DD + h*64 + lg*8;
        qa1[0] = *(const bf16x8*)qp1;
        qa1[1] = *(const bf16x8*)(qp1 + 32);
        const unsigned short* qp2 = Qb + (size_t)(b*SS + qt2*64 + w*16 + lr) * DD + h*64 + lg*8;
        qa2[0] = *(const bf16x8*)qp2;
        qa2[1] = *(const bf16x8*)(qp2 + 32);
    }

    f32x4 oacc[4] = {};
    float mrow[4], lsum[4];
    #pragma unroll
    for (int j = 0; j < 4; ++j) { mrow[j] = -3.0e38f; lsum[j] = 0.f; }

    // prologue: stage kv-tile 0 into buffer 0
    #pragma unroll
    for (int i = 0; i < 2; ++i) {
        const unsigned short* srcK = Kb + (size_t)(b*SS + i*32 + srow) * DD + h*64 + sksw;
        GLOAD16(srcK, &sK[0][i*2048 + w*512]);
        const unsigned short* srcV = Vt + (size_t)(bh*64 + i*32 + srow) * SS + sksw;
        GLOAD16(srcV, &sV[0][i*2048 + w*512]);
    }
    int cur = 0;

    for (int s = 0; s < total; ++s) {
        const bool h2 = (s >= steps1);
        const int kt = h2 ? s - steps1 : s;
        const int qth = h2 ? qt2 : qt1;

        __syncthreads();   // drains vmcnt: buf[cur] staged; all waves done reading buf[cur^1]

        // prefetch the next tile in the fused sequence into buf[cur^1]
        if (s + 1 < total) {
            const int sn = s + 1;
            const int ktn = (sn >= steps1) ? sn - steps1 : sn;
            #pragma unroll
            for (int i = 0; i < 2; ++i) {
                const unsigned short* srcK = Kb + (size_t)(b*SS + ktn*64 + i*32 + srow) * DD + h*64 + sksw;
                GLOAD16(srcK, &sK[cur^1][i*2048 + w*512]);
                const unsigned short* srcV = Vt + (size_t)(bh*64 + i*32 + srow) * SS + ktn*64 + sksw;
                GLOAD16(srcV, &sV[cur^1][i*2048 + w*512]);
            }
        }

        bf16x8 qf0 = h2 ? qa2[0] : qa1[0];
        bf16x8 qf1 = h2 ? qa2[1] : qa1[1];

        f32x4 sacc[4] = {};
        __builtin_amdgcn_s_setprio(1);
        #pragma unroll
        for (int ni = 0; ni < 4; ++ni) {
            bf16x8 kf0 = *(const bf16x8*)&sK[cur][(ni*16 + lr)*64 + ((lg*8) ^ rdsw)];
            sacc[ni] = __builtin_amdgcn_mfma_f32_16x16x32_bf16(qf0, kf0, sacc[ni], 0, 0, 0);
            bf16x8 kf1 = *(const bf16x8*)&sK[cur][(ni*16 + lr)*64 + ((32 + lg*8) ^ rdsw)];
            sacc[ni] = __builtin_amdgcn_mfma_f32_16x16x32_bf16(qf1, kf1, sacc[ni], 0, 0, 0);
        }
        __builtin_amdgcn_s_setprio(0);

        const bool diag = (kt == qth);
        float tmx[4];
        #pragma unroll
        for (int j = 0; j < 4; ++j) {
            int qrow = qth*64 + w*16 + lg*4 + j;
            float mx = -3.0e38f;
            #pragma unroll
            for (int ni = 0; ni < 4; ++ni) {
                float v = sacc[ni][j];
                if (diag) {
                    int kcol = kt*64 + ni*16 + lr;
                    if (kcol > qrow) v = -1e30f;
                }
                sacc[ni][j] = v;
                mx = fmaxf(mx, v);
            }
            mx = fmaxf(mx, __shfl_xor(mx, 1));
            mx = fmaxf(mx, __shfl_xor(mx, 2));
            mx = fmaxf(mx, __shfl_xor(mx, 4));
            mx = fmaxf(mx, __shfl_xor(mx, 8));
            tmx[j] = mx;
        }
        // T13 defer-max: rescale only if some row grew by more than THR
        float growth = tmx[0] - mrow[0];
        #pragma unroll
        for (int j = 1; j < 4; ++j) growth = fmaxf(growth, tmx[j] - mrow[j]);
        if (!__all(growth <= THR)) {
            #pragma unroll
            for (int j = 0; j < 4; ++j) {
                float mnew = fmaxf(mrow[j], tmx[j]);
                float alpha = exp2f(mrow[j] - mnew);
                lsum[j] *= alpha;
                mrow[j] = mnew;
                #pragma unroll
                for (int di = 0; di < 4; ++di) oacc[di][j] *= alpha;
            }
        }
        // P = exp2(S - m); per-lane partial sums only (cross-lane reduce deferred to epilogue)
        #pragma unroll
        for (int j = 0; j < 4; ++j) {
            float rs = 0.f;
            #pragma unroll
            for (int ni = 0; ni < 4; ++ni) {
                float p = exp2f(sacc[ni][j] - mrow[j]);
                sacc[ni][j] = p;
                rs += p;
            }
            lsum[j] += rs;
        }
        // P -> LDS (bf16), swizzled both sides (per-wave buffer, no block barrier needed)
        #pragma unroll
        for (int j = 0; j < 4; ++j) {
            int rp = lg*4 + j;
            #pragma unroll
            for (int ni = 0; ni < 4; ++ni)
                sP[w][rp*64 + ((ni*16 + lr) ^ ((rp & 7)*8))] = f2bf(sacc[ni][j]);
        }
        asm volatile("s_waitcnt lgkmcnt(0)" ::: "memory");
        __builtin_amdgcn_sched_barrier(0);
        __builtin_amdgcn_s_setprio(1);
        #pragma unroll
        for (int kk = 0; kk < 2; ++kk) {
            bf16x8 pf = *(const bf16x8*)&sP[w][lr*64 + ((kk*32 + lg*8) ^ rdsw)];
            #pragma unroll
            for (int di = 0; di < 4; ++di) {
                bf16x8 vf = *(const bf16x8*)&sV[cur][(di*16 + lr)*64 + ((kk*32 + lg*8) ^ rdsw)];
                oacc[di] = __builtin_amdgcn_mfma_f32_16x16x32_bf16(pf, vf, oacc[di], 0, 0, 0);
            }
        }
        __builtin_amdgcn_s_setprio(0);

        // half epilogue: reduce lsum across lr lanes, normalize, write O, reset state
        if (s == steps1 - 1 || s == total - 1) {
            #pragma unroll
            for (int j = 0; j < 4; ++j) {
                float t = lsum[j];
                t += __shfl_xor(t, 1);
                t += __shfl_xor(t, 2);
                t += __shfl_xor(t, 4);
                t += __shfl_xor(t, 8);
                float inv = 1.f / t;
                size_t row = (size_t)(b*SS + qth*64 + w*16 + lg*4 + j);
                #pragma unroll
                for (int di = 0; di < 4; ++di)
                    Ob[row * DD + h*64 + di*16 + lr] = f2bf(oacc[di][j] * inv);
                mrow[j] = -3.0e38f;
                lsum[j] = 0.f;
            }
            #pragma unroll
            for (int di = 0; di < 4; ++di)
                oacc[di] = f32x4{0.f, 0.f, 0.f, 0.f};
        }
        cur ^= 1;
    }
}

// ---------------------------------------------------------------- launch
extern "C" void kernel_launch(void* const* d_in, const int* in_sizes, int n_in,
                              void* d_out, int out_size, void* d_ws, size_t ws_size,
                              hipStream_t stream)
{
    const float* x  = (const float*)d_in[0];
    // d_in[1] = mask (causal tril; implemented analytically)
    const int* pids = (const int*)d_in[2];
    const float* wq = (const float*)d_in[3];
    const float* wk = (const float*)d_in[4];
    const float* wv = (const float*)d_in[5];
    const float* wo = (const float*)d_in[6];
    const float* bo = (const float*)d_in[7];
    float* out = (float*)d_out;

    char* ws = (char*)d_ws;
    unsigned short* xb   = (unsigned short*)(ws);                        // 8 MB
    unsigned short* wqkv = (unsigned short*)(ws + (size_t)( 8u<<20));    // 6 MB
    unsigned short* wob  = (unsigned short*)(ws + (size_t)(14u<<20));    // 2 MB
    unsigned short* qkvp = (unsigned short*)(ws + (size_t)(16u<<20));    // 24 MB
    unsigned short* Qb   = (unsigned short*)(ws + (size_t)(40u<<20));    // 8 MB
    unsigned short* Kb   = (unsigned short*)(ws + (size_t)(48u<<20));    // 8 MB
    unsigned short* Vt   = (unsigned short*)(ws + (size_t)(56u<<20));    // 8 MB
    float* tabc          = (float*)(ws + (size_t)(64u<<20));             // 256 KB
    float* tabs          = (float*)(ws + (size_t)(64u<<20) + (256u<<10));// 256 KB
    unsigned short* Ob   = xb;  // alias: x_bf16 dead after QKV GEMM

    cast_all<<<dim3(4096), dim3(256), 0, stream>>>(x, wq, wk, wv, wo, xb, wqkv, wob);
    rope_table<<<dim3(256), dim3(256), 0, stream>>>(tabc, tabs);
    gemm_bt<0><<<dim3(NQKV/128, MROWS/128), dim3(256), 0, stream>>>(
        xb, wqkv, (void*)qkvp, (const float*)nullptr, MROWS, NQKV, DD);
    rope_qk<<<dim3(2048), dim3(256), 0, stream>>>(qkvp, pids, tabc, tabs, Qb, Kb);
    v_transpose<<<dim3(32, 32), dim3(256), 0, stream>>>(qkvp, Vt);
    attn_fwd<<<dim3(512), dim3(256), 0, stream>>>(Qb, Kb, Vt, Ob);
    gemm_bt<1><<<dim3(DD/128, MROWS/128), dim3(256), 0, stream>>>(
        Ob, wob, (void*)out, bo, MROWS, DD, DD);
}

// Round 8
// 169.570 us; speedup vs baseline: 1.1147x; 1.0091x over previous
//
#include <hip/hip_runtime.h>
#include <hip/hip_bf16.h>
#include <cstdint>

#define BB 2
#define SS 2048
#define DD 1024
#define HH 16
#define DK 64
#define MROWS (BB*SS)        // 4096
#define NQKV  (3*DD)         // 3072

typedef __bf16 bf16x8 __attribute__((ext_vector_type(8)));
typedef float  f32x4  __attribute__((ext_vector_type(4)));

static __device__ __forceinline__ unsigned short f2bf(float f) {
    __bf16 h = (__bf16)f;
    return __builtin_bit_cast(unsigned short, h);
}
static __device__ __forceinline__ float bf2f(unsigned short u) {
    return (float)__builtin_bit_cast(__bf16, u);
}

#define GLOAD16(gsrc, ldst) \
    __builtin_amdgcn_global_load_lds((const __attribute__((address_space(1))) void*)(gsrc), \
                                     (__attribute__((address_space(3))) void*)(ldst), 16, 0, 0)

// ---------------------------------------------------------------- cast x + weights to bf16
__global__ void cast_all(const float* __restrict__ x,  const float* __restrict__ wq,
                         const float* __restrict__ wk, const float* __restrict__ wv,
                         const float* __restrict__ wo,
                         unsigned short* __restrict__ xb, unsigned short* __restrict__ wqkv,
                         unsigned short* __restrict__ wob)
{
    const int NX = MROWS * DD;      // 4194304
    const int NW = DD * DD;         // 1048576
    const int total = (NX + 4 * NW) / 8;
    for (int i = blockIdx.x * blockDim.x + threadIdx.x; i < total; i += gridDim.x * blockDim.x) {
        int base = i * 8;
        const float* src; unsigned short* dst; int off;
        if      (base < NX)          { src = x;  dst = xb;          off = base; }
        else if (base < NX + NW)     { src = wq; dst = wqkv;        off = base - NX; }
        else if (base < NX + 2*NW)   { src = wk; dst = wqkv + NW;   off = base - NX - NW; }
        else if (base < NX + 3*NW)   { src = wv; dst = wqkv + 2*NW; off = base - NX - 2*NW; }
        else                         { src = wo; dst = wob;         off = base - NX - 3*NW; }
        float4 a = *(const float4*)(src + off);
        float4 b = *(const float4*)(src + off + 4);
        union { unsigned short s[8]; uint4 v; } u;
        u.s[0] = f2bf(a.x); u.s[1] = f2bf(a.y); u.s[2] = f2bf(a.z); u.s[3] = f2bf(a.w);
        u.s[4] = f2bf(b.x); u.s[5] = f2bf(b.y); u.s[6] = f2bf(b.z); u.s[7] = f2bf(b.w);
        *(uint4*)(dst + off) = u.v;
    }
}

// ---------------------------------------------------------------- RoPE cos/sin table [2048][32]
__global__ void rope_table(float* __restrict__ tabc, float* __restrict__ tabs)
{
    int i = blockIdx.x * blockDim.x + threadIdx.x;   // 65536 threads
    int s = i >> 5, d = i & 31;
    float inv = exp2f(-(float)d * (13.287712379549449f / 32.f));  // 10000^(-d/32)
    float ang = (float)s * inv;
    tabc[i] = cosf(ang);
    tabs[i] = sinf(ang);
}

// ---------------------------------------------------------------- GEMM  C[M][N] = A[M][K] * B[N][K]^T
// 128x128 tile, BK=64, 4 waves (2x2), 16x16x32 bf16 MFMA, global_load_lds staging.
template<int OUTF32>
__global__ __launch_bounds__(256) void gemm_bt(
    const unsigned short* __restrict__ A, const unsigned short* __restrict__ Bm,
    void* __restrict__ Cout, const float* __restrict__ bias,
    int M, int N, int K)
{
    __shared__ __align__(16) unsigned short sA[128 * 64];
    __shared__ __align__(16) unsigned short sB[128 * 64];
    const int tid = threadIdx.x;
    const int w = tid >> 6, l = tid & 63;
    const int wm = w >> 1, wn = w & 1;
    const int lr = l & 15, lg = l >> 4;
    const int mBase = blockIdx.y * 128, nBase = blockIdx.x * 128;
    const int srow = tid >> 3;           // 0..31
    const int skof = (tid & 7) * 8;      // element offset in K

    f32x4 acc[4][4] = {};

    for (int kt = 0; kt < K; kt += 64) {
        __syncthreads();
        #pragma unroll
        for (int i = 0; i < 4; ++i) {
            const unsigned short* srcA = A + (size_t)(mBase + i*32 + srow) * K + kt + skof;
            GLOAD16(srcA, &sA[i*2048 + w*512]);
            const unsigned short* srcB = Bm + (size_t)(nBase + i*32 + srow) * K + kt + skof;
            GLOAD16(srcB, &sB[i*2048 + w*512]);
        }
        __syncthreads();
        #pragma unroll
        for (int kk = 0; kk < 2; ++kk) {
            bf16x8 af[4], bfv[4];
            #pragma unroll
            for (int mi = 0; mi < 4; ++mi)
                af[mi] = *(const bf16x8*)&sA[(wm*64 + mi*16 + lr)*64 + kk*32 + lg*8];
            #pragma unroll
            for (int ni = 0; ni < 4; ++ni)
                bfv[ni] = *(const bf16x8*)&sB[(wn*64 + ni*16 + lr)*64 + kk*32 + lg*8];
            #pragma unroll
            for (int mi = 0; mi < 4; ++mi)
                #pragma unroll
                for (int ni = 0; ni < 4; ++ni)
                    acc[mi][ni] = __builtin_amdgcn_mfma_f32_16x16x32_bf16(af[mi], bfv[ni], acc[mi][ni], 0, 0, 0);
        }
    }
    #pragma unroll
    for (int mi = 0; mi < 4; ++mi) {
        #pragma unroll
        for (int j = 0; j < 4; ++j) {
            int row = mBase + wm*64 + mi*16 + lg*4 + j;
            #pragma unroll
            for (int ni = 0; ni < 4; ++ni) {
                int col = nBase + wn*64 + ni*16 + lr;
                float v = acc[mi][ni][j];
                if (OUTF32) ((float*)Cout)[(size_t)row * N + col] = v + bias[col];
                else        ((unsigned short*)Cout)[(size_t)row * N + col] = f2bf(v);
            }
        }
    }
}

// ---------------------------------------------------------------- RoPE on Q,K (vectorized)
// Q pre-scaled by (1/sqrt(dk)) * log2(e) so attention works in the exp2 domain.
__global__ void rope_qk(const unsigned short* __restrict__ qkv,
                        const int* __restrict__ pids,
                        const float* __restrict__ tabc, const float* __restrict__ tabs,
                        unsigned short* __restrict__ Qb, unsigned short* __restrict__ Kb)
{
    int i = blockIdx.x * blockDim.x + threadIdx.x;   // 524288 threads
    int cb = i & 3;
    int h  = (i >> 2) & 15;
    int isK = (i >> 6) & 1;
    int r  = i >> 7;
    int pos = pids[r];
    int dbase = cb * 8;

    const unsigned short* src = qkv + (size_t)r * NQKV + isK * DD + h * 64 + dbase;
    union { unsigned short u[8]; uint4 v; } a, bq, o1, o2;
    a.v  = *(const uint4*)src;
    bq.v = *(const uint4*)(src + 32);
    float cs[8], sn[8];
    *(float4*)&cs[0] = *(const float4*)(tabc + pos*32 + dbase);
    *(float4*)&cs[4] = *(const float4*)(tabc + pos*32 + dbase + 4);
    *(float4*)&sn[0] = *(const float4*)(tabs + pos*32 + dbase);
    *(float4*)&sn[4] = *(const float4*)(tabs + pos*32 + dbase + 4);
    float scale = isK ? 1.0f : 0.1803368801111244f;   // 0.125 * log2(e)
    #pragma unroll
    for (int j = 0; j < 8; ++j) {
        float v1 = bf2f(a.u[j]), v2 = bf2f(bq.u[j]);
        o1.u[j] = f2bf((v1*cs[j] - v2*sn[j]) * scale);
        o2.u[j] = f2bf((v2*cs[j] + v1*sn[j]) * scale);
    }
    unsigned short* dst = (isK ? Kb : Qb) + (size_t)r * DD + h * 64 + dbase;
    *(uint4*)dst        = o1.v;
    *(uint4*)(dst + 32) = o2.v;
}

// ---------------------------------------------------------------- V transpose via chunk-swizzled LDS tile
// qkv [4096][3072] (V at col 2048) -> Vt [32*64][2048]
__global__ __launch_bounds__(256) void v_transpose(
    const unsigned short* __restrict__ qkv, unsigned short* __restrict__ Vt)
{
    __shared__ __align__(16) unsigned short sT[64 * 64];
    const int bh = blockIdx.y;          // 0..31
    const int st = blockIdx.x;          // 0..31 (s-tile)
    const int b = bh >> 4, h = bh & 15;
    const int tid = threadIdx.x;
    #pragma unroll
    for (int i = 0; i < 2; ++i) {
        int c = tid + i*256;            // chunk 0..511
        int s = c >> 3, cb = c & 7;
        const unsigned short* src = qkv + (size_t)(b*SS + st*64 + s) * NQKV + 2*DD + h*64 + cb*8;
        uint4 v = *(const uint4*)src;
        *(uint4*)&sT[s*64 + ((cb ^ (s >> 3)) * 8)] = v;   // chunk-swizzled store
    }
    __syncthreads();
    #pragma unroll
    for (int i = 0; i < 2; ++i) {
        int c = tid + i*256;
        int d = c >> 3, sb = c & 7;
        union { unsigned short u[8]; uint4 v; } o;
        #pragma unroll
        for (int e = 0; e < 8; ++e) {
            int s = sb*8 + e;
            o.u[e] = sT[s*64 + (((d >> 3) ^ (s >> 3)) * 8) + (d & 7)];
        }
        *(uint4*)(Vt + (size_t)(bh*64 + d) * SS + st*64 + sb*8) = o.v;
    }
}

// ---------------------------------------------------------------- flash attention fwd (causal)
// 1024 blocks, placement-proof balanced: bid -> xcd=bid&7, g=(bid>>3)>>5, s=(bid>>3)&31,
// bh = xcd*4+g, qt = (g&1) ? 31-s : s.  Under round-robin block->CU placement, CU k gets
// qt in {k, 31-k, k, 31-k} -> exactly 66 kv-steps per CU.  4 blocks/CU x 40KB LDS = 160KB.
// Double-buffered K/V staging (1 barrier/step, prefetch issued right after it), exp2
// softmax, defer-max, deferred cross-lane lsum, diag step peeled, 32-bit staged addressing.
__global__ __launch_bounds__(256) void attn_fwd(
    const unsigned short* __restrict__ Qb,   // [4096][1024], pre-scaled by 0.125*log2e
    const unsigned short* __restrict__ Kb,   // [4096][1024]
    const unsigned short* __restrict__ Vt,   // [2048][2048]
    unsigned short* __restrict__ Ob)         // [4096][1024]
{
    __shared__ __align__(16) unsigned short sK[2][64 * 64];
    __shared__ __align__(16) unsigned short sV[2][64 * 64];
    __shared__ __align__(16) unsigned short sP[4][16 * 64];
    const int tid = threadIdx.x;
    const int w = tid >> 6, l = tid & 63;
    const int lr = l & 15, lg = l >> 4;

    const int xcd = blockIdx.x & 7;
    const int c   = blockIdx.x >> 3;         // 0..127
    const int g   = c >> 5;                  // 0..3
    const int s_  = c & 31;                  // 0..31
    const int qt  = (g & 1) ? (31 - s_) : s_;
    const int bh  = xcd * 4 + g;
    const int b = bh >> 4, h = bh & 15;

    const int srow = tid >> 3;
    const int skof = (tid & 7) * 8;
    const int sksw = skof ^ ((srow & 7) * 8);   // pre-swizzled staging col (elements)
    const int rdsw = (lr & 7) * 8;              // read-side XOR term
    const float THR = 12.0f;                    // defer-max threshold (log2 units)

    // 32-bit staging base offsets (i = 0,1 halves of the 64-row tile)
    const unsigned kBase0 = (unsigned)((b*SS + srow) * DD + h*64 + sksw);
    const unsigned kBase1 = kBase0 + (unsigned)(32 * DD);
    const unsigned vBase0 = (unsigned)((bh*64 + srow) * SS + sksw);
    const unsigned vBase1 = vBase0 + (unsigned)(32 * SS);

    // Q fragments, loaded once
    bf16x8 qf0, qf1;
    {
        const unsigned short* qp = Qb + (size_t)(b*SS + qt*64 + w*16 + lr) * DD + h*64 + lg*8;
        qf0 = *(const bf16x8*)qp;
        qf1 = *(const bf16x8*)(qp + 32);
    }
    const int qrowbase = qt*64 + w*16 + lg*4;

    f32x4 oacc[4] = {};
    float mrow[4], lsum[4];
    #pragma unroll
    for (int j = 0; j < 4; ++j) { mrow[j] = -3.0e38f; lsum[j] = 0.f; }

    int cur = 0;

    // prologue: stage kv-tile 0 into buffer 0
    GLOAD16(Kb + kBase0, &sK[0][w*512]);
    GLOAD16(Kb + kBase1, &sK[0][2048 + w*512]);
    GLOAD16(Vt + vBase0, &sV[0][w*512]);
    GLOAD16(Vt + vBase1, &sV[0][2048 + w*512]);

    // one kv-step; pf = next kv-tile to prefetch (-1 = none); DIAG = apply causal mask
    auto kv_step = [&](int kt, bool diag, int pf) {
        __syncthreads();   // drains vmcnt: buf[cur] staged; all waves done with buf[cur^1]
        if (pf >= 0) {
            unsigned ko = (unsigned)pf << 16;   // pf * 64 * DD
            unsigned vo = (unsigned)pf << 6;    // pf * 64
            GLOAD16(Kb + kBase0 + ko, &sK[cur^1][w*512]);
            GLOAD16(Kb + kBase1 + ko, &sK[cur^1][2048 + w*512]);
            GLOAD16(Vt + vBase0 + vo, &sV[cur^1][w*512]);
            GLOAD16(Vt + vBase1 + vo, &sV[cur^1][2048 + w*512]);
        }

        f32x4 sacc[4] = {};
        __builtin_amdgcn_s_setprio(1);
        #pragma unroll
        for (int ni = 0; ni < 4; ++ni) {
            bf16x8 kf0 = *(const bf16x8*)&sK[cur][(ni*16 + lr)*64 + ((lg*8) ^ rdsw)];
            sacc[ni] = __builtin_amdgcn_mfma_f32_16x16x32_bf16(qf0, kf0, sacc[ni], 0, 0, 0);
            bf16x8 kf1 = *(const bf16x8*)&sK[cur][(ni*16 + lr)*64 + ((32 + lg*8) ^ rdsw)];
            sacc[ni] = __builtin_amdgcn_mfma_f32_16x16x32_bf16(qf1, kf1, sacc[ni], 0, 0, 0);
        }
        __builtin_amdgcn_s_setprio(0);

        float tmx[4];
        #pragma unroll
        for (int j = 0; j < 4; ++j) {
            float mx = -3.0e38f;
            if (diag) {
                int qrow = qrowbase + j;
                #pragma unroll
                for (int ni = 0; ni < 4; ++ni) {
                    int kcol = kt*64 + ni*16 + lr;
                    float v = sacc[ni][j];
                    if (kcol > qrow) v = -1e30f;
                    sacc[ni][j] = v;
                    mx = fmaxf(mx, v);
                }
            } else {
                #pragma unroll
                for (int ni = 0; ni < 4; ++ni) mx = fmaxf(mx, sacc[ni][j]);
            }
            mx = fmaxf(mx, __shfl_xor(mx, 1));
            mx = fmaxf(mx, __shfl_xor(mx, 2));
            mx = fmaxf(mx, __shfl_xor(mx, 4));
            mx = fmaxf(mx, __shfl_xor(mx, 8));
            tmx[j] = mx;
        }
        float growth = tmx[0] - mrow[0];
        #pragma unroll
        for (int j = 1; j < 4; ++j) growth = fmaxf(growth, tmx[j] - mrow[j]);
        if (!__all(growth <= THR)) {
            #pragma unroll
            for (int j = 0; j < 4; ++j) {
                float mnew = fmaxf(mrow[j], tmx[j]);
                float alpha = exp2f(mrow[j] - mnew);
                lsum[j] *= alpha;
                mrow[j] = mnew;
                #pragma unroll
                for (int di = 0; di < 4; ++di) oacc[di][j] *= alpha;
            }
        }
        #pragma unroll
        for (int j = 0; j < 4; ++j) {
            float rs = 0.f;
            #pragma unroll
            for (int ni = 0; ni < 4; ++ni) {
                float p = exp2f(sacc[ni][j] - mrow[j]);
                sacc[ni][j] = p;
                rs += p;
            }
            lsum[j] += rs;
        }
        #pragma unroll
        for (int j = 0; j < 4; ++j) {
            int rp = lg*4 + j;
            #pragma unroll
            for (int ni = 0; ni < 4; ++ni)
                sP[w][rp*64 + ((ni*16 + lr) ^ ((rp & 7)*8))] = f2bf(sacc[ni][j]);
        }
        asm volatile("s_waitcnt lgkmcnt(0)" ::: "memory");
        __builtin_amdgcn_sched_barrier(0);
        __builtin_amdgcn_s_setprio(1);
        #pragma unroll
        for (int kk = 0; kk < 2; ++kk) {
            bf16x8 pf2 = *(const bf16x8*)&sP[w][lr*64 + ((kk*32 + lg*8) ^ rdsw)];
            #pragma unroll
            for (int di = 0; di < 4; ++di) {
                bf16x8 vf = *(const bf16x8*)&sV[cur][(di*16 + lr)*64 + ((kk*32 + lg*8) ^ rdsw)];
                oacc[di] = __builtin_amdgcn_mfma_f32_16x16x32_bf16(pf2, vf, oacc[di], 0, 0, 0);
            }
        }
        __builtin_amdgcn_s_setprio(0);
        cur ^= 1;
    };

    for (int kt = 0; kt < qt; ++kt) kv_step(kt, false, kt + 1);
    kv_step(qt, true, -1);   // diagonal step, no further prefetch

    // epilogue: reduce lsum across lr lanes, normalize, write O
    #pragma unroll
    for (int j = 0; j < 4; ++j) {
        float t = lsum[j];
        t += __shfl_xor(t, 1);
        t += __shfl_xor(t, 2);
        t += __shfl_xor(t, 4);
        t += __shfl_xor(t, 8);
        float inv = 1.f / t;
        size_t row = (size_t)(b*SS + qt*64 + w*16 + lg*4 + j);
        #pragma unroll
        for (int di = 0; di < 4; ++di)
            Ob[row * DD + h*64 + di*16 + lr] = f2bf(oacc[di][j] * inv);
    }
}

// ---------------------------------------------------------------- launch
extern "C" void kernel_launch(void* const* d_in, const int* in_sizes, int n_in,
                              void* d_out, int out_size, void* d_ws, size_t ws_size,
                              hipStream_t stream)
{
    const float* x  = (const float*)d_in[0];
    // d_in[1] = mask (causal tril; implemented analytically)
    const int* pids = (const int*)d_in[2];
    const float* wq = (const float*)d_in[3];
    const float* wk = (const float*)d_in[4];
    const float* wv = (const float*)d_in[5];
    const float* wo = (const float*)d_in[6];
    const float* bo = (const float*)d_in[7];
    float* out = (float*)d_out;

    char* ws = (char*)d_ws;
    unsigned short* xb   = (unsigned short*)(ws);                        // 8 MB
    unsigned short* wqkv = (unsigned short*)(ws + (size_t)( 8u<<20));    // 6 MB
    unsigned short* wob  = (unsigned short*)(ws + (size_t)(14u<<20));    // 2 MB
    unsigned short* qkvp = (unsigned short*)(ws + (size_t)(16u<<20));    // 24 MB
    unsigned short* Qb   = (unsigned short*)(ws + (size_t)(40u<<20));    // 8 MB
    unsigned short* Kb   = (unsigned short*)(ws + (size_t)(48u<<20));    // 8 MB
    unsigned short* Vt   = (unsigned short*)(ws + (size_t)(56u<<20));    // 8 MB
    float* tabc          = (float*)(ws + (size_t)(64u<<20));             // 256 KB
    float* tabs          = (float*)(ws + (size_t)(64u<<20) + (256u<<10));// 256 KB
    unsigned short* Ob   = xb;  // alias: x_bf16 dead after QKV GEMM

    cast_all<<<dim3(4096), dim3(256), 0, stream>>>(x, wq, wk, wv, wo, xb, wqkv, wob);
    rope_table<<<dim3(256), dim3(256), 0, stream>>>(tabc, tabs);
    gemm_bt<0><<<dim3(NQKV/128, MROWS/128), dim3(256), 0, stream>>>(
        xb, wqkv, (void*)qkvp, (const float*)nullptr, MROWS, NQKV, DD);
    rope_qk<<<dim3(2048), dim3(256), 0, stream>>>(qkvp, pids, tabc, tabs, Qb, Kb);
    v_transpose<<<dim3(32, 32), dim3(256), 0, stream>>>(qkvp, Vt);
    attn_fwd<<<dim3(1024), dim3(256), 0, stream>>>(Qb, Kb, Vt, Ob);
    gemm_bt<1><<<dim3(DD/128, MROWS/128), dim3(256), 0, stream>>>(
        Ob, wob, (void*)out, bo, MROWS, DD, DD);
}

// Round 10
// 154.238 us; speedup vs baseline: 1.2255x; 1.0994x over previous
//
#include <hip/hip_runtime.h>
#include <hip/hip_bf16.h>
#include <cstdint>

#define BB 2
#define SS 2048
#define DD 1024
#define HH 16
#define DK 64
#define MROWS (BB*SS)        // 4096
#define NQKV  (3*DD)         // 3072

typedef __bf16 bf16x8 __attribute__((ext_vector_type(8)));
typedef float  f32x4  __attribute__((ext_vector_type(4)));
typedef float  f32x16 __attribute__((ext_vector_type(16)));
typedef unsigned u32x2 __attribute__((ext_vector_type(2)));

static __device__ __forceinline__ unsigned short f2bf(float f) {
    __bf16 h = (__bf16)f;
    return __builtin_bit_cast(unsigned short, h);
}
static __device__ __forceinline__ float bf2f(unsigned short u) {
    return (float)__builtin_bit_cast(__bf16, u);
}

#define GLOAD16(gsrc, ldst) \
    __builtin_amdgcn_global_load_lds((const __attribute__((address_space(1))) void*)(gsrc), \
                                     (__attribute__((address_space(3))) void*)(ldst), 16, 0, 0)

// v_permlane32_swap_b32 semantics (HK-usage-consistent): FIRST operand's HIGH half
// swaps with SECOND operand's LOW half:
//   lanes 0..31 :  x' = x(own),            y' = x(partner = lane+32)
//   lanes 32..63:  x' = y(partner = lane-32), y' = y(own)
static __device__ __forceinline__ void pl32_swap(unsigned &x, unsigned &y) {
#if __has_builtin(__builtin_amdgcn_permlane32_swap)
    u32x2 r = __builtin_amdgcn_permlane32_swap(x, y, false, false);
    x = r[0]; y = r[1];
#else
    asm volatile("v_permlane32_swap_b32 %0, %1" : "+v"(x), "+v"(y));
#endif
}
// value held by partner lane (lane ^ 32); q=lane&31 preserved
static __device__ __forceinline__ float swap_half(float v, bool hi) {
    unsigned x = __builtin_bit_cast(unsigned, v), y = x;
    pl32_swap(x, y);
    return __builtin_bit_cast(float, hi ? x : y);
}
// T12: build PV B-frag (P[k = kbase + (l>>5)*8 + e][q=lane&31], 8 bf16) from the 8 f32
// C-layout regs p[BASE..BASE+7], where p[BASE+r] = P[kbase + 4*hi5 + (r&3) + 8*(r>>2)][q].
//   x0=pk(p0,p1), y0=pk(p4,p5); pl(x0,y0) -> x0 = w0, y0 = w2 (both halves verified)
//   x1=pk(p2,p3), y1=pk(p6,p7); pl(x1,y1) -> x1 = w1, y1 = w3
template<int BASE> static __device__ __forceinline__ bf16x8 cvt_chunk(const f32x16 &p) {
    unsigned x0, y0, x1, y1;
    asm("v_cvt_pk_bf16_f32 %0, %1, %2" : "=v"(x0) : "v"(p[BASE+0]), "v"(p[BASE+1]));
    asm("v_cvt_pk_bf16_f32 %0, %1, %2" : "=v"(y0) : "v"(p[BASE+4]), "v"(p[BASE+5]));
    asm("v_cvt_pk_bf16_f32 %0, %1, %2" : "=v"(x1) : "v"(p[BASE+2]), "v"(p[BASE+3]));
    asm("v_cvt_pk_bf16_f32 %0, %1, %2" : "=v"(y1) : "v"(p[BASE+6]), "v"(p[BASE+7]));
    pl32_swap(x0, y0);
    pl32_swap(x1, y1);
    union { unsigned u[4]; bf16x8 v; } r;
    r.u[0] = x0; r.u[1] = x1; r.u[2] = y0; r.u[3] = y1;
    return r.v;
}

// ---------------------------------------------------------------- cast x + weights to bf16
__global__ void cast_all(const float* __restrict__ x,  const float* __restrict__ wq,
                         const float* __restrict__ wk, const float* __restrict__ wv,
                         const float* __restrict__ wo,
                         unsigned short* __restrict__ xb, unsigned short* __restrict__ wqkv,
                         unsigned short* __restrict__ wob)
{
    const int NX = MROWS * DD;      // 4194304
    const int NW = DD * DD;         // 1048576
    const int total = (NX + 4 * NW) / 8;
    for (int i = blockIdx.x * blockDim.x + threadIdx.x; i < total; i += gridDim.x * blockDim.x) {
        int base = i * 8;
        const float* src; unsigned short* dst; int off;
        if      (base < NX)          { src = x;  dst = xb;          off = base; }
        else if (base < NX + NW)     { src = wq; dst = wqkv;        off = base - NX; }
        else if (base < NX + 2*NW)   { src = wk; dst = wqkv + NW;   off = base - NX - NW; }
        else if (base < NX + 3*NW)   { src = wv; dst = wqkv + 2*NW; off = base - NX - 2*NW; }
        else                         { src = wo; dst = wob;         off = base - NX - 3*NW; }
        float4 a = *(const float4*)(src + off);
        float4 b = *(const float4*)(src + off + 4);
        union { unsigned short s[8]; uint4 v; } u;
        u.s[0] = f2bf(a.x); u.s[1] = f2bf(a.y); u.s[2] = f2bf(a.z); u.s[3] = f2bf(a.w);
        u.s[4] = f2bf(b.x); u.s[5] = f2bf(b.y); u.s[6] = f2bf(b.z); u.s[7] = f2bf(b.w);
        *(uint4*)(dst + off) = u.v;
    }
}

// ---------------------------------------------------------------- RoPE cos/sin table [2048][32]
__global__ void rope_table(float* __restrict__ tabc, float* __restrict__ tabs)
{
    int i = blockIdx.x * blockDim.x + threadIdx.x;   // 65536 threads
    int s = i >> 5, d = i & 31;
    float inv = exp2f(-(float)d * (13.287712379549449f / 32.f));  // 10000^(-d/32)
    float ang = (float)s * inv;
    tabc[i] = cosf(ang);
    tabs[i] = sinf(ang);
}

// ---------------------------------------------------------------- GEMM  C[M][N] = A[M][K] * B[N][K]^T
template<int OUTF32>
__global__ __launch_bounds__(256) void gemm_bt(
    const unsigned short* __restrict__ A, const unsigned short* __restrict__ Bm,
    void* __restrict__ Cout, const float* __restrict__ bias,
    int M, int N, int K)
{
    __shared__ __align__(16) unsigned short sA[128 * 64];
    __shared__ __align__(16) unsigned short sB[128 * 64];
    const int tid = threadIdx.x;
    const int w = tid >> 6, l = tid & 63;
    const int wm = w >> 1, wn = w & 1;
    const int lr = l & 15, lg = l >> 4;
    const int mBase = blockIdx.y * 128, nBase = blockIdx.x * 128;
    const int srow = tid >> 3;           // 0..31
    const int skof = (tid & 7) * 8;      // element offset in K

    f32x4 acc[4][4] = {};

    for (int kt = 0; kt < K; kt += 64) {
        __syncthreads();
        #pragma unroll
        for (int i = 0; i < 4; ++i) {
            const unsigned short* srcA = A + (size_t)(mBase + i*32 + srow) * K + kt + skof;
            GLOAD16(srcA, &sA[i*2048 + w*512]);
            const unsigned short* srcB = Bm + (size_t)(nBase + i*32 + srow) * K + kt + skof;
            GLOAD16(srcB, &sB[i*2048 + w*512]);
        }
        __syncthreads();
        #pragma unroll
        for (int kk = 0; kk < 2; ++kk) {
            bf16x8 af[4], bfv[4];
            #pragma unroll
            for (int mi = 0; mi < 4; ++mi)
                af[mi] = *(const bf16x8*)&sA[(wm*64 + mi*16 + lr)*64 + kk*32 + lg*8];
            #pragma unroll
            for (int ni = 0; ni < 4; ++ni)
                bfv[ni] = *(const bf16x8*)&sB[(wn*64 + ni*16 + lr)*64 + kk*32 + lg*8];
            #pragma unroll
            for (int mi = 0; mi < 4; ++mi)
                #pragma unroll
                for (int ni = 0; ni < 4; ++ni)
                    acc[mi][ni] = __builtin_amdgcn_mfma_f32_16x16x32_bf16(af[mi], bfv[ni], acc[mi][ni], 0, 0, 0);
        }
    }
    #pragma unroll
    for (int mi = 0; mi < 4; ++mi) {
        #pragma unroll
        for (int j = 0; j < 4; ++j) {
            int row = mBase + wm*64 + mi*16 + lg*4 + j;
            #pragma unroll
            for (int ni = 0; ni < 4; ++ni) {
                int col = nBase + wn*64 + ni*16 + lr;
                float v = acc[mi][ni][j];
                if (OUTF32) ((float*)Cout)[(size_t)row * N + col] = v + bias[col];
                else        ((unsigned short*)Cout)[(size_t)row * N + col] = f2bf(v);
            }
        }
    }
}

// ---------------------------------------------------------------- RoPE on Q,K (vectorized)
// Q pre-scaled by (1/sqrt(dk)) * log2(e) so attention works in the exp2 domain.
__global__ void rope_qk(const unsigned short* __restrict__ qkv,
                        const int* __restrict__ pids,
                        const float* __restrict__ tabc, const float* __restrict__ tabs,
                        unsigned short* __restrict__ Qb, unsigned short* __restrict__ Kb)
{
    int i = blockIdx.x * blockDim.x + threadIdx.x;   // 524288 threads
    int cb = i & 3;
    int h  = (i >> 2) & 15;
    int isK = (i >> 6) & 1;
    int r  = i >> 7;
    int pos = pids[r];
    int dbase = cb * 8;

    const unsigned short* src = qkv + (size_t)r * NQKV + isK * DD + h * 64 + dbase;
    union { unsigned short u[8]; uint4 v; } a, bq, o1, o2;
    a.v  = *(const uint4*)src;
    bq.v = *(const uint4*)(src + 32);
    float cs[8], sn[8];
    *(float4*)&cs[0] = *(const float4*)(tabc + pos*32 + dbase);
    *(float4*)&cs[4] = *(const float4*)(tabc + pos*32 + dbase + 4);
    *(float4*)&sn[0] = *(const float4*)(tabs + pos*32 + dbase);
    *(float4*)&sn[4] = *(const float4*)(tabs + pos*32 + dbase + 4);
    float scale = isK ? 1.0f : 0.1803368801111244f;   // 0.125 * log2(e)
    #pragma unroll
    for (int j = 0; j < 8; ++j) {
        float v1 = bf2f(a.u[j]), v2 = bf2f(bq.u[j]);
        o1.u[j] = f2bf((v1*cs[j] - v2*sn[j]) * scale);
        o2.u[j] = f2bf((v2*cs[j] + v1*sn[j]) * scale);
    }
    unsigned short* dst = (isK ? Kb : Qb) + (size_t)r * DD + h * 64 + dbase;
    *(uint4*)dst        = o1.v;
    *(uint4*)(dst + 32) = o2.v;
}

// ---------------------------------------------------------------- V transpose via chunk-swizzled LDS tile
__global__ __launch_bounds__(256) void v_transpose(
    const unsigned short* __restrict__ qkv, unsigned short* __restrict__ Vt)
{
    __shared__ __align__(16) unsigned short sT[64 * 64];
    const int bh = blockIdx.y;          // 0..31
    const int st = blockIdx.x;          // 0..31 (s-tile)
    const int b = bh >> 4, h = bh & 15;
    const int tid = threadIdx.x;
    #pragma unroll
    for (int i = 0; i < 2; ++i) {
        int c = tid + i*256;            // chunk 0..511
        int s = c >> 3, cb = c & 7;
        const unsigned short* src = qkv + (size_t)(b*SS + st*64 + s) * NQKV + 2*DD + h*64 + cb*8;
        uint4 v = *(const uint4*)src;
        *(uint4*)&sT[s*64 + ((cb ^ (s >> 3)) * 8)] = v;   // chunk-swizzled store
    }
    __syncthreads();
    #pragma unroll
    for (int i = 0; i < 2; ++i) {
        int c = tid + i*256;
        int d = c >> 3, sb = c & 7;
        union { unsigned short u[8]; uint4 v; } o;
        #pragma unroll
        for (int e = 0; e < 8; ++e) {
            int s = sb*8 + e;
            o.u[e] = sT[s*64 + (((d >> 3) ^ (s >> 3)) * 8) + (d & 7)];
        }
        *(uint4*)(Vt + (size_t)(bh*64 + d) * SS + st*64 + sb*8) = o.v;
    }
}

// ---------------------------------------------------------------- flash attention fwd (causal)
// T12 structure: 32x32x16 MFMA, swapped operands. QK^T computed as mfma(K,Q) so each lane
// holds P[k-half][q=lane&31] -> softmax fully in-register (fmax tree + permlane32_swap, no
// LDS/shfl). PV computed as mfma(V^T, P) -> O^T with q=lane&31 (per-lane lsum/rescale OK);
// P->B-frag via v_cvt_pk_bf16_f32 + permlane32_swap (no sP round-trip).
// 1024 blocks x 128 threads (2 waves x 32 q-rows = 64-row q tile), R8's placement-proof
// balanced mapping, double-buffered K/V staging, exp2 softmax, defer-max.
__global__ __launch_bounds__(128, 2) void attn_fwd(
    const unsigned short* __restrict__ Qb,   // [4096][1024], pre-scaled by 0.125*log2e
    const unsigned short* __restrict__ Kb,   // [4096][1024]
    const unsigned short* __restrict__ Vt,   // [2048][2048]
    unsigned short* __restrict__ Ob)         // [4096][1024]
{
    __shared__ __align__(16) unsigned short sK[2][64 * 64];
    __shared__ __align__(16) unsigned short sV[2][64 * 64];
    const int tid = threadIdx.x;
    const int w = tid >> 6, l = tid & 63;
    const int lq = l & 31;
    const int hi5 = l >> 5;
    const bool hb = hi5 != 0;

    const int xcd = blockIdx.x & 7;
    const int c   = blockIdx.x >> 3;         // 0..127
    const int g   = c >> 5;                  // 0..3
    const int s_  = c & 31;                  // 0..31
    const int qt  = (g & 1) ? (31 - s_) : s_;
    const int bh  = xcd * 4 + g;
    const int b = bh >> 4, h = bh & 15;

    const int srow2 = tid >> 3;              // 0..15
    const int skof  = (tid & 7) * 8;
    const int sksw  = skof ^ ((srow2 & 7) * 8);  // pre-swizzled staging col (elements)
    const int sw    = (lq & 7) * 8;              // read-side XOR term
    const float THR = 12.0f;

    const unsigned kR = (unsigned)((b*SS + srow2) * DD + h*64 + sksw);
    const unsigned vR = (unsigned)((bh*64 + srow2) * SS + sksw);

    // Q fragments: Q[q=lq][dk = dkc*16 + hi5*8 + e]
    bf16x8 qf[4];
    {
        const unsigned short* qp = Qb + (size_t)(b*SS + qt*64 + w*32 + lq) * DD + h*64 + hi5*8;
        #pragma unroll
        for (int dkc = 0; dkc < 4; ++dkc)
            qf[dkc] = *(const bf16x8*)(qp + dkc*16);
    }
    const int q_lane = qt*64 + w*32 + lq;

    f32x16 o0 = {}, o1 = {};
    float mrow = -3.0e38f, lsum = 0.f;
    int cur = 0;

    // prologue: stage kv-tile 0 into buffer 0
    #pragma unroll
    for (int i = 0; i < 4; ++i) {
        GLOAD16(Kb + kR + (unsigned)(i << 14), &sK[0][i*1024 + w*512]);
        GLOAD16(Vt + vR + (unsigned)(i << 15), &sV[0][i*1024 + w*512]);
    }

    for (int kt = 0; kt <= qt; ++kt) {
        __syncthreads();   // vmcnt drained: buf[cur] staged; all waves done with buf[cur^1]
        if (kt < qt) {
            unsigned ko = (unsigned)(kt + 1) << 16;   // (kt+1)*64*DD
            unsigned vo = (unsigned)(kt + 1) << 6;    // (kt+1)*64
            #pragma unroll
            for (int i = 0; i < 4; ++i) {
                GLOAD16(Kb + kR + ko + (unsigned)(i << 14), &sK[cur^1][i*1024 + w*512]);
                GLOAD16(Vt + vR + vo + (unsigned)(i << 15), &sV[cur^1][i*1024 + w*512]);
            }
        }

        // QK^T swapped: p[ka] = mfma(K-frag, Q-frag); lane holds S[k=ka*32+crow(r,hi5)][q=lq]
        f32x16 p0 = {}, p1 = {};
        __builtin_amdgcn_s_setprio(1);
        #pragma unroll
        for (int dkc = 0; dkc < 4; ++dkc) {
            bf16x8 k0 = *(const bf16x8*)&sK[cur][lq*64 + ((dkc*16 + hi5*8) ^ sw)];
            p0 = __builtin_amdgcn_mfma_f32_32x32x16_bf16(k0, qf[dkc], p0, 0, 0, 0);
        }
        #pragma unroll
        for (int dkc = 0; dkc < 4; ++dkc) {
            bf16x8 k1 = *(const bf16x8*)&sK[cur][(32 + lq)*64 + ((dkc*16 + hi5*8) ^ sw)];
            p1 = __builtin_amdgcn_mfma_f32_32x32x16_bf16(k1, qf[dkc], p1, 0, 0, 0);
        }
        __builtin_amdgcn_s_setprio(0);

        if (kt == qt) {   // diagonal: mask k > q
            const int kb0 = kt*64 + 4*hi5;
            #pragma unroll
            for (int r = 0; r < 16; ++r) {
                const int cr = (r & 3) + 8*(r >> 2);
                if (kb0 + cr > q_lane)      p0[r] = -1e30f;
                if (kb0 + 32 + cr > q_lane) p1[r] = -1e30f;
            }
        }

        // row max: in-lane tree over 32 + partner swap
        float tt[16];
        #pragma unroll
        for (int r = 0; r < 16; ++r) tt[r] = fmaxf(p0[r], p1[r]);
        #pragma unroll
        for (int s2 = 8; s2 >= 1; s2 >>= 1)
            #pragma unroll
            for (int r = 0; r < 8; ++r)
                if (r < s2) tt[r] = fmaxf(tt[r], tt[r + s2]);
        float tmx = fmaxf(tt[0], swap_half(tt[0], hb));

        // defer-max (T13)
        float growth = tmx - mrow;
        if (!__all(growth <= THR)) {
            float mnew = fmaxf(mrow, tmx);
            float alpha = exp2f(mrow - mnew);
            lsum *= alpha;
            mrow = mnew;
            #pragma unroll
            for (int r = 0; r < 16; ++r) { o0[r] *= alpha; o1[r] *= alpha; }
        }

        // P = exp2(S - m), per-lane partial sum (partner-half added at epilogue)
        #pragma unroll
        for (int r = 0; r < 16; ++r) {
            p0[r] = exp2f(p0[r] - mrow);
            p1[r] = exp2f(p1[r] - mrow);
        }
        float st[16];
        #pragma unroll
        for (int r = 0; r < 16; ++r) st[r] = p0[r] + p1[r];
        #pragma unroll
        for (int s2 = 8; s2 >= 1; s2 >>= 1)
            #pragma unroll
            for (int r = 0; r < 8; ++r)
                if (r < s2) st[r] += st[r + s2];
        lsum += st[0];

        // PV swapped: O^T[d][q] += mfma(V^T-frag, P-frag); in-register P conversion (T12)
        __builtin_amdgcn_s_setprio(1);
        {
            bf16x8 pa, vf;
            pa = cvt_chunk<0>(p0);   // k 0..15
            vf = *(const bf16x8*)&sV[cur][lq*64 + ((0*16 + hi5*8) ^ sw)];
            o0 = __builtin_amdgcn_mfma_f32_32x32x16_bf16(vf, pa, o0, 0, 0, 0);
            vf = *(const bf16x8*)&sV[cur][(32 + lq)*64 + ((0*16 + hi5*8) ^ sw)];
            o1 = __builtin_amdgcn_mfma_f32_32x32x16_bf16(vf, pa, o1, 0, 0, 0);
            pa = cvt_chunk<8>(p0);   // k 16..31
            vf = *(const bf16x8*)&sV[cur][lq*64 + ((1*16 + hi5*8) ^ sw)];
            o0 = __builtin_amdgcn_mfma_f32_32x32x16_bf16(vf, pa, o0, 0, 0, 0);
            vf = *(const bf16x8*)&sV[cur][(32 + lq)*64 + ((1*16 + hi5*8) ^ sw)];
            o1 = __builtin_amdgcn_mfma_f32_32x32x16_bf16(vf, pa, o1, 0, 0, 0);
            pa = cvt_chunk<0>(p1);   // k 32..47
            vf = *(const bf16x8*)&sV[cur][lq*64 + ((2*16 + hi5*8) ^ sw)];
            o0 = __builtin_amdgcn_mfma_f32_32x32x16_bf16(vf, pa, o0, 0, 0, 0);
            vf = *(const bf16x8*)&sV[cur][(32 + lq)*64 + ((2*16 + hi5*8) ^ sw)];
            o1 = __builtin_amdgcn_mfma_f32_32x32x16_bf16(vf, pa, o1, 0, 0, 0);
            pa = cvt_chunk<8>(p1);   // k 48..63
            vf = *(const bf16x8*)&sV[cur][lq*64 + ((3*16 + hi5*8) ^ sw)];
            o0 = __builtin_amdgcn_mfma_f32_32x32x16_bf16(vf, pa, o0, 0, 0, 0);
            vf = *(const bf16x8*)&sV[cur][(32 + lq)*64 + ((3*16 + hi5*8) ^ sw)];
            o1 = __builtin_amdgcn_mfma_f32_32x32x16_bf16(vf, pa, o1, 0, 0, 0);
        }
        __builtin_amdgcn_s_setprio(0);
        cur ^= 1;
    }

    // ---- epilogue: normalize, LDS-transpose O (reuse sK), coalesced store
    __syncthreads();   // all waves done reading sK/sV
    float ls = lsum + swap_half(lsum, hb);
    float inv = 1.f / ls;
    unsigned short* sO = &sK[0][0] + w * 2048;   // per-wave [32 q][64 d] bf16

    // lane holds O[q=lq][d = nd*32 + (r&3) + 8*(r>>2) + 4*hi5]
    #pragma unroll
    for (int g2 = 0; g2 < 4; ++g2) {
        unsigned ua, ub; uint2 t2;
        float v0 = o0[g2*4+0]*inv, v1 = o0[g2*4+1]*inv, v2 = o0[g2*4+2]*inv, v3 = o0[g2*4+3]*inv;
        asm("v_cvt_pk_bf16_f32 %0, %1, %2" : "=v"(ua) : "v"(v0), "v"(v1));
        asm("v_cvt_pk_bf16_f32 %0, %1, %2" : "=v"(ub) : "v"(v2), "v"(v3));
        t2.x = ua; t2.y = ub;
        *(uint2*)&sO[lq*64 + g2*8 + hi5*4] = t2;
        float w0 = o1[g2*4+0]*inv, w1 = o1[g2*4+1]*inv, w2 = o1[g2*4+2]*inv, w3 = o1[g2*4+3]*inv;
        asm("v_cvt_pk_bf16_f32 %0, %1, %2" : "=v"(ua) : "v"(w0), "v"(w1));
        asm("v_cvt_pk_bf16_f32 %0, %1, %2" : "=v"(ub) : "v"(w2), "v"(w3));
        t2.x = ua; t2.y = ub;
        *(uint2*)&sO[lq*64 + 32 + g2*8 + hi5*4] = t2;
    }
    asm volatile("s_waitcnt lgkmcnt(0)" ::: "memory");
    __builtin_amdgcn_sched_barrier(0);

    const int row = l >> 1, cb2 = (l & 1) * 32;
    const unsigned short* sOr = sO + row*64 + cb2;
    unsigned short* gp = Ob + (size_t)(b*SS + qt*64 + w*32 + row) * DD + h*64 + cb2;
    #pragma unroll
    for (int c2 = 0; c2 < 4; ++c2)
        *(uint4*)(gp + c2*8) = *(const uint4*)(sOr + c2*8);
}

// ---------------------------------------------------------------- launch
extern "C" void kernel_launch(void* const* d_in, const int* in_sizes, int n_in,
                              void* d_out, int out_size, void* d_ws, size_t ws_size,
                              hipStream_t stream)
{
    const float* x  = (const float*)d_in[0];
    // d_in[1] = mask (causal tril; implemented analytically)
    const int* pids = (const int*)d_in[2];
    const float* wq = (const float*)d_in[3];
    const float* wk = (const float*)d_in[4];
    const float* wv = (const float*)d_in[5];
    const float* wo = (const float*)d_in[6];
    const float* bo = (const float*)d_in[7];
    float* out = (float*)d_out;

    char* ws = (char*)d_ws;
    unsigned short* xb   = (unsigned short*)(ws);                        // 8 MB
    unsigned short* wqkv = (unsigned short*)(ws + (size_t)( 8u<<20));    // 6 MB
    unsigned short* wob  = (unsigned short*)(ws + (size_t)(14u<<20));    // 2 MB
    unsigned short* qkvp = (unsigned short*)(ws + (size_t)(16u<<20));    // 24 MB
    unsigned short* Qb   = (unsigned short*)(ws + (size_t)(40u<<20));    // 8 MB
    unsigned short* Kb   = (unsigned short*)(ws + (size_t)(48u<<20));    // 8 MB
    unsigned short* Vt   = (unsigned short*)(ws + (size_t)(56u<<20));    // 8 MB
    float* tabc          = (float*)(ws + (size_t)(64u<<20));             // 256 KB
    float* tabs          = (float*)(ws + (size_t)(64u<<20) + (256u<<10));// 256 KB
    unsigned short* Ob   = xb;  // alias: x_bf16 dead after QKV GEMM

    cast_all<<<dim3(4096), dim3(256), 0, stream>>>(x, wq, wk, wv, wo, xb, wqkv, wob);
    rope_table<<<dim3(256), dim3(256), 0, stream>>>(tabc, tabs);
    gemm_bt<0><<<dim3(NQKV/128, MROWS/128), dim3(256), 0, stream>>>(
        xb, wqkv, (void*)qkvp, (const float*)nullptr, MROWS, NQKV, DD);
    rope_qk<<<dim3(2048), dim3(256), 0, stream>>>(qkvp, pids, tabc, tabs, Qb, Kb);
    v_transpose<<<dim3(32, 32), dim3(256), 0, stream>>>(qkvp, Vt);
    attn_fwd<<<dim3(1024), dim3(128), 0, stream>>>(Qb, Kb, Vt, Ob);
    gemm_bt<1><<<dim3(DD/128, MROWS/128), dim3(256), 0, stream>>>(
        Ob, wob, (void*)out, bo, MROWS, DD, DD);
}

// Round 11
// 151.539 us; speedup vs baseline: 1.2473x; 1.0178x over previous
//
#include <hip/hip_runtime.h>
#include <hip/hip_bf16.h>
#include <cstdint>

#define BB 2
#define SS 2048
#define DD 1024
#define HH 16
#define DK 64
#define MROWS (BB*SS)        // 4096
#define NQKV  (3*DD)         // 3072

typedef __bf16 bf16x8 __attribute__((ext_vector_type(8)));
typedef float  f32x4  __attribute__((ext_vector_type(4)));
typedef float  f32x16 __attribute__((ext_vector_type(16)));
typedef unsigned u32x2 __attribute__((ext_vector_type(2)));

static __device__ __forceinline__ unsigned short f2bf(float f) {
    __bf16 h = (__bf16)f;
    return __builtin_bit_cast(unsigned short, h);
}
static __device__ __forceinline__ float bf2f(unsigned short u) {
    return (float)__builtin_bit_cast(__bf16, u);
}

#define GLOAD16(gsrc, ldst) \
    __builtin_amdgcn_global_load_lds((const __attribute__((address_space(1))) void*)(gsrc), \
                                     (__attribute__((address_space(3))) void*)(ldst), 16, 0, 0)

// v_permlane32_swap_b32: first operand's HIGH half swaps with second operand's LOW half.
static __device__ __forceinline__ void pl32_swap(unsigned &x, unsigned &y) {
#if __has_builtin(__builtin_amdgcn_permlane32_swap)
    u32x2 r = __builtin_amdgcn_permlane32_swap(x, y, false, false);
    x = r[0]; y = r[1];
#else
    asm volatile("v_permlane32_swap_b32 %0, %1" : "+v"(x), "+v"(y));
#endif
}
static __device__ __forceinline__ float swap_half(float v, bool hi) {
    unsigned x = __builtin_bit_cast(unsigned, v), y = x;
    pl32_swap(x, y);
    return __builtin_bit_cast(float, hi ? x : y);
}
// T12: build PV B-frag from 8 f32 C-layout regs (verified R10).
template<int BASE> static __device__ __forceinline__ bf16x8 cvt_chunk(const f32x16 &p) {
    unsigned x0, y0, x1, y1;
    asm("v_cvt_pk_bf16_f32 %0, %1, %2" : "=v"(x0) : "v"(p[BASE+0]), "v"(p[BASE+1]));
    asm("v_cvt_pk_bf16_f32 %0, %1, %2" : "=v"(y0) : "v"(p[BASE+4]), "v"(p[BASE+5]));
    asm("v_cvt_pk_bf16_f32 %0, %1, %2" : "=v"(x1) : "v"(p[BASE+2]), "v"(p[BASE+3]));
    asm("v_cvt_pk_bf16_f32 %0, %1, %2" : "=v"(y1) : "v"(p[BASE+6]), "v"(p[BASE+7]));
    pl32_swap(x0, y0);
    pl32_swap(x1, y1);
    union { unsigned u[4]; bf16x8 v; } r;
    r.u[0] = x0; r.u[1] = x1; r.u[2] = y0; r.u[3] = y1;
    return r.v;
}

// ---------------------------------------------------------------- cast x + weights to bf16
__global__ void cast_all(const float* __restrict__ x,  const float* __restrict__ wq,
                         const float* __restrict__ wk, const float* __restrict__ wv,
                         const float* __restrict__ wo,
                         unsigned short* __restrict__ xb, unsigned short* __restrict__ wqkv,
                         unsigned short* __restrict__ wob)
{
    const int NX = MROWS * DD;      // 4194304
    const int NW = DD * DD;         // 1048576
    const int total = (NX + 4 * NW) / 8;
    for (int i = blockIdx.x * blockDim.x + threadIdx.x; i < total; i += gridDim.x * blockDim.x) {
        int base = i * 8;
        const float* src; unsigned short* dst; int off;
        if      (base < NX)          { src = x;  dst = xb;          off = base; }
        else if (base < NX + NW)     { src = wq; dst = wqkv;        off = base - NX; }
        else if (base < NX + 2*NW)   { src = wk; dst = wqkv + NW;   off = base - NX - NW; }
        else if (base < NX + 3*NW)   { src = wv; dst = wqkv + 2*NW; off = base - NX - 2*NW; }
        else                         { src = wo; dst = wob;         off = base - NX - 3*NW; }
        float4 a = *(const float4*)(src + off);
        float4 b = *(const float4*)(src + off + 4);
        union { unsigned short s[8]; uint4 v; } u;
        u.s[0] = f2bf(a.x); u.s[1] = f2bf(a.y); u.s[2] = f2bf(a.z); u.s[3] = f2bf(a.w);
        u.s[4] = f2bf(b.x); u.s[5] = f2bf(b.y); u.s[6] = f2bf(b.z); u.s[7] = f2bf(b.w);
        *(uint4*)(dst + off) = u.v;
    }
}

// ---------------------------------------------------------------- RoPE cos/sin table [2048][32]
__global__ void rope_table(float* __restrict__ tabc, float* __restrict__ tabs)
{
    int i = blockIdx.x * blockDim.x + threadIdx.x;   // 65536 threads
    int s = i >> 5, d = i & 31;
    float inv = exp2f(-(float)d * (13.287712379549449f / 32.f));  // 10000^(-d/32)
    float ang = (float)s * inv;
    tabc[i] = cosf(ang);
    tabs[i] = sinf(ang);
}

// ---------------------------------------------------------------- fused QKV GEMM + RoPE epilogue
// C = xb[4096][1024] * wqkv[3072][1024]^T; 128x128 tile, BK=64, 4 waves, T1 XCD swizzle.
// Epilogue: each wave's col span = one 64-wide head slice; acc[mi][ni] and acc[mi][ni+2]
// are the (d, d+32) rotate-half partners -> RoPE fully in-register. Q scaled by
// 0.125*log2(e); writes Qb/Kb directly. V region written plain to Vr.
__global__ __launch_bounds__(256) void gemm_qkv(
    const unsigned short* __restrict__ A, const unsigned short* __restrict__ Bm,
    const int* __restrict__ pids,
    const float* __restrict__ tabc, const float* __restrict__ tabs,
    unsigned short* __restrict__ Qb, unsigned short* __restrict__ Kb,
    unsigned short* __restrict__ Vr)
{
    __shared__ __align__(16) unsigned short sA[128 * 64];
    __shared__ __align__(16) unsigned short sB[128 * 64];
    const int tid = threadIdx.x;
    const int w = tid >> 6, l = tid & 63;
    const int wm = w >> 1, wn = w & 1;
    const int lr = l & 15, lg = l >> 4;
    // T1: 768 blocks = 8 XCDs x 96
    const int swz = (blockIdx.x & 7) * 96 + (blockIdx.x >> 3);
    const int bx = swz % 24, by = swz / 24;
    const int mBase = by * 128, nBase = bx * 128;
    const int srow = tid >> 3;
    const int skof = (tid & 7) * 8;

    f32x4 acc[4][4] = {};

    for (int kt = 0; kt < DD; kt += 64) {
        __syncthreads();
        #pragma unroll
        for (int i = 0; i < 4; ++i) {
            const unsigned short* srcA = A + (size_t)(mBase + i*32 + srow) * DD + kt + skof;
            GLOAD16(srcA, &sA[i*2048 + w*512]);
            const unsigned short* srcB = Bm + (size_t)(nBase + i*32 + srow) * DD + kt + skof;
            GLOAD16(srcB, &sB[i*2048 + w*512]);
        }
        __syncthreads();
        #pragma unroll
        for (int kk = 0; kk < 2; ++kk) {
            bf16x8 af[4], bfv[4];
            #pragma unroll
            for (int mi = 0; mi < 4; ++mi)
                af[mi] = *(const bf16x8*)&sA[(wm*64 + mi*16 + lr)*64 + kk*32 + lg*8];
            #pragma unroll
            for (int ni = 0; ni < 4; ++ni)
                bfv[ni] = *(const bf16x8*)&sB[(wn*64 + ni*16 + lr)*64 + kk*32 + lg*8];
            #pragma unroll
            for (int mi = 0; mi < 4; ++mi)
                #pragma unroll
                for (int ni = 0; ni < 4; ++ni)
                    acc[mi][ni] = __builtin_amdgcn_mfma_f32_16x16x32_bf16(af[mi], bfv[ni], acc[mi][ni], 0, 0, 0);
        }
    }

    if (bx < 16) {
        // Q (bx<8) or K (8..15) with in-register RoPE
        const bool isQ = bx < 8;
        unsigned short* dst = isQ ? Qb : Kb;
        const float qsc = isQ ? 0.1803368801111244f : 1.0f;   // 0.125*log2e on Q only
        const int colbase = (bx & 7)*128 + wn*64;             // head*64 within [0,1024)
        #pragma unroll
        for (int mi = 0; mi < 4; ++mi) {
            #pragma unroll
            for (int j = 0; j < 4; ++j) {
                int row = mBase + wm*64 + mi*16 + lg*4 + j;
                int pos = pids[row];
                #pragma unroll
                for (int ni = 0; ni < 2; ++ni) {
                    int d = ni*16 + lr;                        // 0..31
                    float cc = tabc[pos*32 + d];
                    float sn = tabs[pos*32 + d];
                    float a  = acc[mi][ni][j];
                    float bb = acc[mi][ni+2][j];
                    dst[(size_t)row * DD + colbase + d]      = f2bf((a*cc - bb*sn) * qsc);
                    dst[(size_t)row * DD + colbase + d + 32] = f2bf((bb*cc + a*sn) * qsc);
                }
            }
        }
    } else {
        // V region: plain bf16 store to Vr
        const int colbase = (bx - 16)*128 + wn*64;
        #pragma unroll
        for (int mi = 0; mi < 4; ++mi) {
            #pragma unroll
            for (int j = 0; j < 4; ++j) {
                int row = mBase + wm*64 + mi*16 + lg*4 + j;
                #pragma unroll
                for (int ni = 0; ni < 4; ++ni)
                    Vr[(size_t)row * DD + colbase + ni*16 + lr] = f2bf(acc[mi][ni][j]);
            }
        }
    }
}

// ---------------------------------------------------------------- GEMM  C[M][N] = A[M][K]*B[N][K]^T + bias
// (used for output projection; 1-D grid with T1 XCD swizzle)
__global__ __launch_bounds__(256) void gemm_bt(
    const unsigned short* __restrict__ A, const unsigned short* __restrict__ Bm,
    float* __restrict__ Cout, const float* __restrict__ bias,
    int M, int N, int K)
{
    __shared__ __align__(16) unsigned short sA[128 * 64];
    __shared__ __align__(16) unsigned short sB[128 * 64];
    const int tid = threadIdx.x;
    const int w = tid >> 6, l = tid & 63;
    const int wm = w >> 1, wn = w & 1;
    const int lr = l & 15, lg = l >> 4;
    const int nwg = gridDim.x;
    const int cpx = nwg >> 3;
    const int swz = (blockIdx.x & 7) * cpx + (blockIdx.x >> 3);
    const int nbx = N >> 7;
    const int bx = swz % nbx, by = swz / nbx;
    const int mBase = by * 128, nBase = bx * 128;
    const int srow = tid >> 3;
    const int skof = (tid & 7) * 8;

    f32x4 acc[4][4] = {};

    for (int kt = 0; kt < K; kt += 64) {
        __syncthreads();
        #pragma unroll
        for (int i = 0; i < 4; ++i) {
            const unsigned short* srcA = A + (size_t)(mBase + i*32 + srow) * K + kt + skof;
            GLOAD16(srcA, &sA[i*2048 + w*512]);
            const unsigned short* srcB = Bm + (size_t)(nBase + i*32 + srow) * K + kt + skof;
            GLOAD16(srcB, &sB[i*2048 + w*512]);
        }
        __syncthreads();
        #pragma unroll
        for (int kk = 0; kk < 2; ++kk) {
            bf16x8 af[4], bfv[4];
            #pragma unroll
            for (int mi = 0; mi < 4; ++mi)
                af[mi] = *(const bf16x8*)&sA[(wm*64 + mi*16 + lr)*64 + kk*32 + lg*8];
            #pragma unroll
            for (int ni = 0; ni < 4; ++ni)
                bfv[ni] = *(const bf16x8*)&sB[(wn*64 + ni*16 + lr)*64 + kk*32 + lg*8];
            #pragma unroll
            for (int mi = 0; mi < 4; ++mi)
                #pragma unroll
                for (int ni = 0; ni < 4; ++ni)
                    acc[mi][ni] = __builtin_amdgcn_mfma_f32_16x16x32_bf16(af[mi], bfv[ni], acc[mi][ni], 0, 0, 0);
        }
    }
    #pragma unroll
    for (int mi = 0; mi < 4; ++mi) {
        #pragma unroll
        for (int j = 0; j < 4; ++j) {
            int row = mBase + wm*64 + mi*16 + lg*4 + j;
            #pragma unroll
            for (int ni = 0; ni < 4; ++ni) {
                int col = nBase + wn*64 + ni*16 + lr;
                Cout[(size_t)row * N + col] = acc[mi][ni][j] + bias[col];
            }
        }
    }
}

// ---------------------------------------------------------------- V transpose via chunk-swizzled LDS tile
// Vr [4096][1024] -> Vt [32*64][2048]
__global__ __launch_bounds__(256) void v_transpose(
    const unsigned short* __restrict__ Vr, unsigned short* __restrict__ Vt)
{
    __shared__ __align__(16) unsigned short sT[64 * 64];
    const int bh = blockIdx.y;          // 0..31
    const int st = blockIdx.x;          // 0..31 (s-tile)
    const int b = bh >> 4, h = bh & 15;
    const int tid = threadIdx.x;
    #pragma unroll
    for (int i = 0; i < 2; ++i) {
        int c = tid + i*256;            // chunk 0..511
        int s = c >> 3, cb = c & 7;
        const unsigned short* src = Vr + (size_t)(b*SS + st*64 + s) * DD + h*64 + cb*8;
        uint4 v = *(const uint4*)src;
        *(uint4*)&sT[s*64 + ((cb ^ (s >> 3)) * 8)] = v;   // chunk-swizzled store
    }
    __syncthreads();
    #pragma unroll
    for (int i = 0; i < 2; ++i) {
        int c = tid + i*256;
        int d = c >> 3, sb = c & 7;
        union { unsigned short u[8]; uint4 v; } o;
        #pragma unroll
        for (int e = 0; e < 8; ++e) {
            int s = sb*8 + e;
            o.u[e] = sT[s*64 + (((d >> 3) ^ (s >> 3)) * 8) + (d & 7)];
        }
        *(uint4*)(Vt + (size_t)(bh*64 + d) * SS + st*64 + sb*8) = o.v;
    }
}

// ---------------------------------------------------------------- flash attention fwd (causal)
// T12 structure (unchanged from R10): 32x32x16 swapped-operand MFMA, in-register softmax.
__global__ __launch_bounds__(128, 2) void attn_fwd(
    const unsigned short* __restrict__ Qb,   // [4096][1024], pre-scaled by 0.125*log2e
    const unsigned short* __restrict__ Kb,   // [4096][1024]
    const unsigned short* __restrict__ Vt,   // [2048][2048]
    unsigned short* __restrict__ Ob)         // [4096][1024]
{
    __shared__ __align__(16) unsigned short sK[2][64 * 64];
    __shared__ __align__(16) unsigned short sV[2][64 * 64];
    const int tid = threadIdx.x;
    const int w = tid >> 6, l = tid & 63;
    const int lq = l & 31;
    const int hi5 = l >> 5;
    const bool hb = hi5 != 0;

    const int xcd = blockIdx.x & 7;
    const int c   = blockIdx.x >> 3;         // 0..127
    const int g   = c >> 5;                  // 0..3
    const int s_  = c & 31;                  // 0..31
    const int qt  = (g & 1) ? (31 - s_) : s_;
    const int bh  = xcd * 4 + g;
    const int b = bh >> 4, h = bh & 15;

    const int srow2 = tid >> 3;              // 0..15
    const int skof  = (tid & 7) * 8;
    const int sksw  = skof ^ ((srow2 & 7) * 8);  // pre-swizzled staging col (elements)
    const int sw    = (lq & 7) * 8;              // read-side XOR term
    const float THR = 12.0f;

    const unsigned kR = (unsigned)((b*SS + srow2) * DD + h*64 + sksw);
    const unsigned vR = (unsigned)((bh*64 + srow2) * SS + sksw);

    // Q fragments: Q[q=lq][dk = dkc*16 + hi5*8 + e]
    bf16x8 qf[4];
    {
        const unsigned short* qp = Qb + (size_t)(b*SS + qt*64 + w*32 + lq) * DD + h*64 + hi5*8;
        #pragma unroll
        for (int dkc = 0; dkc < 4; ++dkc)
            qf[dkc] = *(const bf16x8*)(qp + dkc*16);
    }
    const int q_lane = qt*64 + w*32 + lq;

    f32x16 o0 = {}, o1 = {};
    float mrow = -3.0e38f, lsum = 0.f;
    int cur = 0;

    #pragma unroll
    for (int i = 0; i < 4; ++i) {
        GLOAD16(Kb + kR + (unsigned)(i << 14), &sK[0][i*1024 + w*512]);
        GLOAD16(Vt + vR + (unsigned)(i << 15), &sV[0][i*1024 + w*512]);
    }

    for (int kt = 0; kt <= qt; ++kt) {
        __syncthreads();
        if (kt < qt) {
            unsigned ko = (unsigned)(kt + 1) << 16;
            unsigned vo = (unsigned)(kt + 1) << 6;
            #pragma unroll
            for (int i = 0; i < 4; ++i) {
                GLOAD16(Kb + kR + ko + (unsigned)(i << 14), &sK[cur^1][i*1024 + w*512]);
                GLOAD16(Vt + vR + vo + (unsigned)(i << 15), &sV[cur^1][i*1024 + w*512]);
            }
        }

        f32x16 p0 = {}, p1 = {};
        __builtin_amdgcn_s_setprio(1);
        #pragma unroll
        for (int dkc = 0; dkc < 4; ++dkc) {
            bf16x8 k0 = *(const bf16x8*)&sK[cur][lq*64 + ((dkc*16 + hi5*8) ^ sw)];
            p0 = __builtin_amdgcn_mfma_f32_32x32x16_bf16(k0, qf[dkc], p0, 0, 0, 0);
        }
        #pragma unroll
        for (int dkc = 0; dkc < 4; ++dkc) {
            bf16x8 k1 = *(const bf16x8*)&sK[cur][(32 + lq)*64 + ((dkc*16 + hi5*8) ^ sw)];
            p1 = __builtin_amdgcn_mfma_f32_32x32x16_bf16(k1, qf[dkc], p1, 0, 0, 0);
        }
        __builtin_amdgcn_s_setprio(0);

        if (kt == qt) {
            const int kb0 = kt*64 + 4*hi5;
            #pragma unroll
            for (int r = 0; r < 16; ++r) {
                const int cr = (r & 3) + 8*(r >> 2);
                if (kb0 + cr > q_lane)      p0[r] = -1e30f;
                if (kb0 + 32 + cr > q_lane) p1[r] = -1e30f;
            }
        }

        float tt[16];
        #pragma unroll
        for (int r = 0; r < 16; ++r) tt[r] = fmaxf(p0[r], p1[r]);
        #pragma unroll
        for (int s2 = 8; s2 >= 1; s2 >>= 1)
            #pragma unroll
            for (int r = 0; r < 8; ++r)
                if (r < s2) tt[r] = fmaxf(tt[r], tt[r + s2]);
        float tmx = fmaxf(tt[0], swap_half(tt[0], hb));

        float growth = tmx - mrow;
        if (!__all(growth <= THR)) {
            float mnew = fmaxf(mrow, tmx);
            float alpha = exp2f(mrow - mnew);
            lsum *= alpha;
            mrow = mnew;
            #pragma unroll
            for (int r = 0; r < 16; ++r) { o0[r] *= alpha; o1[r] *= alpha; }
        }

        #pragma unroll
        for (int r = 0; r < 16; ++r) {
            p0[r] = exp2f(p0[r] - mrow);
            p1[r] = exp2f(p1[r] - mrow);
        }
        float st[16];
        #pragma unroll
        for (int r = 0; r < 16; ++r) st[r] = p0[r] + p1[r];
        #pragma unroll
        for (int s2 = 8; s2 >= 1; s2 >>= 1)
            #pragma unroll
            for (int r = 0; r < 8; ++r)
                if (r < s2) st[r] += st[r + s2];
        lsum += st[0];

        __builtin_amdgcn_s_setprio(1);
        {
            bf16x8 pa, vf;
            pa = cvt_chunk<0>(p0);   // k 0..15
            vf = *(const bf16x8*)&sV[cur][lq*64 + ((0*16 + hi5*8) ^ sw)];
            o0 = __builtin_amdgcn_mfma_f32_32x32x16_bf16(vf, pa, o0, 0, 0, 0);
            vf = *(const bf16x8*)&sV[cur][(32 + lq)*64 + ((0*16 + hi5*8) ^ sw)];
            o1 = __builtin_amdgcn_mfma_f32_32x32x16_bf16(vf, pa, o1, 0, 0, 0);
            pa = cvt_chunk<8>(p0);   // k 16..31
            vf = *(const bf16x8*)&sV[cur][lq*64 + ((1*16 + hi5*8) ^ sw)];
            o0 = __builtin_amdgcn_mfma_f32_32x32x16_bf16(vf, pa, o0, 0, 0, 0);
            vf = *(const bf16x8*)&sV[cur][(32 + lq)*64 + ((1*16 + hi5*8) ^ sw)];
            o1 = __builtin_amdgcn_mfma_f32_32x32x16_bf16(vf, pa, o1, 0, 0, 0);
            pa = cvt_chunk<0>(p1);   // k 32..47
            vf = *(const bf16x8*)&sV[cur][lq*64 + ((2*16 + hi5*8) ^ sw)];
            o0 = __builtin_amdgcn_mfma_f32_32x32x16_bf16(vf, pa, o0, 0, 0, 0);
            vf = *(const bf16x8*)&sV[cur][(32 + lq)*64 + ((2*16 + hi5*8) ^ sw)];
            o1 = __builtin_amdgcn_mfma_f32_32x32x16_bf16(vf, pa, o1, 0, 0, 0);
            pa = cvt_chunk<8>(p1);   // k 48..63
            vf = *(const bf16x8*)&sV[cur][lq*64 + ((3*16 + hi5*8) ^ sw)];
            o0 = __builtin_amdgcn_mfma_f32_32x32x16_bf16(vf, pa, o0, 0, 0, 0);
            vf = *(const bf16x8*)&sV[cur][(32 + lq)*64 + ((3*16 + hi5*8) ^ sw)];
            o1 = __builtin_amdgcn_mfma_f32_32x32x16_bf16(vf, pa, o1, 0, 0, 0);
        }
        __builtin_amdgcn_s_setprio(0);
        cur ^= 1;
    }

    // ---- epilogue: normalize, LDS-transpose O (reuse sK), coalesced store
    __syncthreads();
    float ls = lsum + swap_half(lsum, hb);
    float inv = 1.f / ls;
    unsigned short* sO = &sK[0][0] + w * 2048;   // per-wave [32 q][64 d] bf16

    #pragma unroll
    for (int g2 = 0; g2 < 4; ++g2) {
        unsigned ua, ub; uint2 t2;
        float v0 = o0[g2*4+0]*inv, v1 = o0[g2*4+1]*inv, v2 = o0[g2*4+2]*inv, v3 = o0[g2*4+3]*inv;
        asm("v_cvt_pk_bf16_f32 %0, %1, %2" : "=v"(ua) : "v"(v0), "v"(v1));
        asm("v_cvt_pk_bf16_f32 %0, %1, %2" : "=v"(ub) : "v"(v2), "v"(v3));
        t2.x = ua; t2.y = ub;
        *(uint2*)&sO[lq*64 + g2*8 + hi5*4] = t2;
        float w0 = o1[g2*4+0]*inv, w1 = o1[g2*4+1]*inv, w2 = o1[g2*4+2]*inv, w3 = o1[g2*4+3]*inv;
        asm("v_cvt_pk_bf16_f32 %0, %1, %2" : "=v"(ua) : "v"(w0), "v"(w1));
        asm("v_cvt_pk_bf16_f32 %0, %1, %2" : "=v"(ub) : "v"(w2), "v"(w3));
        t2.x = ua; t2.y = ub;
        *(uint2*)&sO[lq*64 + 32 + g2*8 + hi5*4] = t2;
    }
    asm volatile("s_waitcnt lgkmcnt(0)" ::: "memory");
    __builtin_amdgcn_sched_barrier(0);

    const int row = l >> 1, cb2 = (l & 1) * 32;
    const unsigned short* sOr = sO + row*64 + cb2;
    unsigned short* gp = Ob + (size_t)(b*SS + qt*64 + w*32 + row) * DD + h*64 + cb2;
    #pragma unroll
    for (int c2 = 0; c2 < 4; ++c2)
        *(uint4*)(gp + c2*8) = *(const uint4*)(sOr + c2*8);
}

// ---------------------------------------------------------------- launch
extern "C" void kernel_launch(void* const* d_in, const int* in_sizes, int n_in,
                              void* d_out, int out_size, void* d_ws, size_t ws_size,
                              hipStream_t stream)
{
    const float* x  = (const float*)d_in[0];
    // d_in[1] = mask (causal tril; implemented analytically)
    const int* pids = (const int*)d_in[2];
    const float* wq = (const float*)d_in[3];
    const float* wk = (const float*)d_in[4];
    const float* wv = (const float*)d_in[5];
    const float* wo = (const float*)d_in[6];
    const float* bo = (const float*)d_in[7];
    float* out = (float*)d_out;

    char* ws = (char*)d_ws;
    unsigned short* xb   = (unsigned short*)(ws);                        // 8 MB
    unsigned short* wqkv = (unsigned short*)(ws + (size_t)( 8u<<20));    // 6 MB
    unsigned short* wob  = (unsigned short*)(ws + (size_t)(14u<<20));    // 2 MB
    unsigned short* Vr   = (unsigned short*)(ws + (size_t)(16u<<20));    // 8 MB
    unsigned short* Qb   = (unsigned short*)(ws + (size_t)(40u<<20));    // 8 MB
    unsigned short* Kb   = (unsigned short*)(ws + (size_t)(48u<<20));    // 8 MB
    unsigned short* Vt   = (unsigned short*)(ws + (size_t)(56u<<20));    // 8 MB
    float* tabc          = (float*)(ws + (size_t)(64u<<20));             // 256 KB
    float* tabs          = (float*)(ws + (size_t)(64u<<20) + (256u<<10));// 256 KB
    unsigned short* Ob   = xb;  // alias: x_bf16 dead after QKV GEMM

    cast_all<<<dim3(4096), dim3(256), 0, stream>>>(x, wq, wk, wv, wo, xb, wqkv, wob);
    rope_table<<<dim3(256), dim3(256), 0, stream>>>(tabc, tabs);
    gemm_qkv<<<dim3(768), dim3(256), 0, stream>>>(
        xb, wqkv, pids, tabc, tabs, Qb, Kb, Vr);
    v_transpose<<<dim3(32, 32), dim3(256), 0, stream>>>(Vr, Vt);
    attn_fwd<<<dim3(1024), dim3(128), 0, stream>>>(Qb, Kb, Vt, Ob);
    gemm_bt<<<dim3(256), dim3(256), 0, stream>>>(
        Ob, wob, out, bo, MROWS, DD, DD);
}

// Round 12
// 147.441 us; speedup vs baseline: 1.2820x; 1.0278x over previous
//
#include <hip/hip_runtime.h>
#include <hip/hip_bf16.h>
#include <cstdint>

#define BB 2
#define SS 2048
#define DD 1024
#define HH 16
#define DK 64
#define MROWS (BB*SS)        // 4096
#define NQKV  (3*DD)         // 3072

typedef __bf16 bf16x8 __attribute__((ext_vector_type(8)));
typedef float  f32x4  __attribute__((ext_vector_type(4)));
typedef float  f32x16 __attribute__((ext_vector_type(16)));
typedef unsigned u32x2 __attribute__((ext_vector_type(2)));

static __device__ __forceinline__ unsigned short f2bf(float f) {
    __bf16 h = (__bf16)f;
    return __builtin_bit_cast(unsigned short, h);
}
static __device__ __forceinline__ float bf2f(unsigned short u) {
    return (float)__builtin_bit_cast(__bf16, u);
}

#define GLOAD16(gsrc, ldst) \
    __builtin_amdgcn_global_load_lds((const __attribute__((address_space(1))) void*)(gsrc), \
                                     (__attribute__((address_space(3))) void*)(ldst), 16, 0, 0)

// v_permlane32_swap_b32: first operand's HIGH half swaps with second operand's LOW half.
static __device__ __forceinline__ void pl32_swap(unsigned &x, unsigned &y) {
#if __has_builtin(__builtin_amdgcn_permlane32_swap)
    u32x2 r = __builtin_amdgcn_permlane32_swap(x, y, false, false);
    x = r[0]; y = r[1];
#else
    asm volatile("v_permlane32_swap_b32 %0, %1" : "+v"(x), "+v"(y));
#endif
}
static __device__ __forceinline__ float swap_half(float v, bool hi) {
    unsigned x = __builtin_bit_cast(unsigned, v), y = x;
    pl32_swap(x, y);
    return __builtin_bit_cast(float, hi ? x : y);
}
// T12: build PV B-frag from 8 f32 C-layout regs (verified R10).
template<int BASE> static __device__ __forceinline__ bf16x8 cvt_chunk(const f32x16 &p) {
    unsigned x0, y0, x1, y1;
    asm("v_cvt_pk_bf16_f32 %0, %1, %2" : "=v"(x0) : "v"(p[BASE+0]), "v"(p[BASE+1]));
    asm("v_cvt_pk_bf16_f32 %0, %1, %2" : "=v"(y0) : "v"(p[BASE+4]), "v"(p[BASE+5]));
    asm("v_cvt_pk_bf16_f32 %0, %1, %2" : "=v"(x1) : "v"(p[BASE+2]), "v"(p[BASE+3]));
    asm("v_cvt_pk_bf16_f32 %0, %1, %2" : "=v"(y1) : "v"(p[BASE+6]), "v"(p[BASE+7]));
    pl32_swap(x0, y0);
    pl32_swap(x1, y1);
    union { unsigned u[4]; bf16x8 v; } r;
    r.u[0] = x0; r.u[1] = x1; r.u[2] = y0; r.u[3] = y1;
    return r.v;
}

// ---------------------------------------------------------------- cast x + weights to bf16
__global__ void cast_all(const float* __restrict__ x,  const float* __restrict__ wq,
                         const float* __restrict__ wk, const float* __restrict__ wv,
                         const float* __restrict__ wo,
                         unsigned short* __restrict__ xb, unsigned short* __restrict__ wqkv,
                         unsigned short* __restrict__ wob)
{
    const int NX = MROWS * DD;      // 4194304
    const int NW = DD * DD;         // 1048576
    const int total = (NX + 4 * NW) / 8;
    for (int i = blockIdx.x * blockDim.x + threadIdx.x; i < total; i += gridDim.x * blockDim.x) {
        int base = i * 8;
        const float* src; unsigned short* dst; int off;
        if      (base < NX)          { src = x;  dst = xb;          off = base; }
        else if (base < NX + NW)     { src = wq; dst = wqkv;        off = base - NX; }
        else if (base < NX + 2*NW)   { src = wk; dst = wqkv + NW;   off = base - NX - NW; }
        else if (base < NX + 3*NW)   { src = wv; dst = wqkv + 2*NW; off = base - NX - 2*NW; }
        else                         { src = wo; dst = wob;         off = base - NX - 3*NW; }
        float4 a = *(const float4*)(src + off);
        float4 b = *(const float4*)(src + off + 4);
        union { unsigned short s[8]; uint4 v; } u;
        u.s[0] = f2bf(a.x); u.s[1] = f2bf(a.y); u.s[2] = f2bf(a.z); u.s[3] = f2bf(a.w);
        u.s[4] = f2bf(b.x); u.s[5] = f2bf(b.y); u.s[6] = f2bf(b.z); u.s[7] = f2bf(b.w);
        *(uint4*)(dst + off) = u.v;
    }
}

// ---------------------------------------------------------------- RoPE cos/sin table [2048][32]
__global__ void rope_table(float* __restrict__ tabc, float* __restrict__ tabs)
{
    int i = blockIdx.x * blockDim.x + threadIdx.x;   // 65536 threads
    int s = i >> 5, d = i & 31;
    float inv = exp2f(-(float)d * (13.287712379549449f / 32.f));  // 10000^(-d/32)
    float ang = (float)s * inv;
    tabc[i] = cosf(ang);
    tabs[i] = sinf(ang);
}

// ---------------------------------------------------------------- fused QKV GEMM + RoPE epilogue
// T3-minimum schedule: single barrier per K-step, double-buffered LDS; prefetch of tile
// t+1 issued right after the barrier so its latency hides under tile t's ds_read+MFMA.
__global__ __launch_bounds__(256) void gemm_qkv(
    const unsigned short* __restrict__ A, const unsigned short* __restrict__ Bm,
    const int* __restrict__ pids,
    const float* __restrict__ tabc, const float* __restrict__ tabs,
    unsigned short* __restrict__ Qb, unsigned short* __restrict__ Kb,
    unsigned short* __restrict__ Vr)
{
    __shared__ __align__(16) unsigned short sA[2][128 * 64];
    __shared__ __align__(16) unsigned short sB[2][128 * 64];
    const int tid = threadIdx.x;
    const int w = tid >> 6, l = tid & 63;
    const int wm = w >> 1, wn = w & 1;
    const int lr = l & 15, lg = l >> 4;
    // T1: 768 blocks = 8 XCDs x 96
    const int swz = (blockIdx.x & 7) * 96 + (blockIdx.x >> 3);
    const int bx = swz % 24, by = swz / 24;
    const int mBase = by * 128, nBase = bx * 128;
    const int srow = tid >> 3;
    const int skof = (tid & 7) * 8;

    f32x4 acc[4][4] = {};

    // prologue: stage K-tile 0 into buffer 0
    #pragma unroll
    for (int i = 0; i < 4; ++i) {
        GLOAD16(A  + (size_t)(mBase + i*32 + srow) * DD + skof, &sA[0][i*2048 + w*512]);
        GLOAD16(Bm + (size_t)(nBase + i*32 + srow) * DD + skof, &sB[0][i*2048 + w*512]);
    }
    int cur = 0;

    for (int kt = 0; kt < DD; kt += 64) {
        __syncthreads();   // buf[cur] staged (vmcnt drained); buf[cur^1] free
        if (kt + 64 < DD) {
            #pragma unroll
            for (int i = 0; i < 4; ++i) {
                GLOAD16(A  + (size_t)(mBase + i*32 + srow) * DD + kt + 64 + skof, &sA[cur^1][i*2048 + w*512]);
                GLOAD16(Bm + (size_t)(nBase + i*32 + srow) * DD + kt + 64 + skof, &sB[cur^1][i*2048 + w*512]);
            }
        }
        #pragma unroll
        for (int kk = 0; kk < 2; ++kk) {
            bf16x8 af[4], bfv[4];
            #pragma unroll
            for (int mi = 0; mi < 4; ++mi)
                af[mi] = *(const bf16x8*)&sA[cur][(wm*64 + mi*16 + lr)*64 + kk*32 + lg*8];
            #pragma unroll
            for (int ni = 0; ni < 4; ++ni)
                bfv[ni] = *(const bf16x8*)&sB[cur][(wn*64 + ni*16 + lr)*64 + kk*32 + lg*8];
            #pragma unroll
            for (int mi = 0; mi < 4; ++mi)
                #pragma unroll
                for (int ni = 0; ni < 4; ++ni)
                    acc[mi][ni] = __builtin_amdgcn_mfma_f32_16x16x32_bf16(af[mi], bfv[ni], acc[mi][ni], 0, 0, 0);
        }
        cur ^= 1;
    }

    if (bx < 16) {
        // Q (bx<8) or K (8..15) with in-register RoPE
        const bool isQ = bx < 8;
        unsigned short* dst = isQ ? Qb : Kb;
        const float qsc = isQ ? 0.1803368801111244f : 1.0f;   // 0.125*log2e on Q only
        const int colbase = (bx & 7)*128 + wn*64;             // head*64 within [0,1024)
        #pragma unroll
        for (int mi = 0; mi < 4; ++mi) {
            #pragma unroll
            for (int j = 0; j < 4; ++j) {
                int row = mBase + wm*64 + mi*16 + lg*4 + j;
                int pos = pids[row];
                #pragma unroll
                for (int ni = 0; ni < 2; ++ni) {
                    int d = ni*16 + lr;                        // 0..31
                    float cc = tabc[pos*32 + d];
                    float sn = tabs[pos*32 + d];
                    float a  = acc[mi][ni][j];
                    float bb = acc[mi][ni+2][j];
                    dst[(size_t)row * DD + colbase + d]      = f2bf((a*cc - bb*sn) * qsc);
                    dst[(size_t)row * DD + colbase + d + 32] = f2bf((bb*cc + a*sn) * qsc);
                }
            }
        }
    } else {
        // V region: plain bf16 store to Vr
        const int colbase = (bx - 16)*128 + wn*64;
        #pragma unroll
        for (int mi = 0; mi < 4; ++mi) {
            #pragma unroll
            for (int j = 0; j < 4; ++j) {
                int row = mBase + wm*64 + mi*16 + lg*4 + j;
                #pragma unroll
                for (int ni = 0; ni < 4; ++ni)
                    Vr[(size_t)row * DD + colbase + ni*16 + lr] = f2bf(acc[mi][ni][j]);
            }
        }
    }
}

// ---------------------------------------------------------------- out-proj GEMM + bias (dbuf T3-min loop)
__global__ __launch_bounds__(256) void gemm_bt(
    const unsigned short* __restrict__ A, const unsigned short* __restrict__ Bm,
    float* __restrict__ Cout, const float* __restrict__ bias,
    int M, int N, int K)
{
    __shared__ __align__(16) unsigned short sA[2][128 * 64];
    __shared__ __align__(16) unsigned short sB[2][128 * 64];
    const int tid = threadIdx.x;
    const int w = tid >> 6, l = tid & 63;
    const int wm = w >> 1, wn = w & 1;
    const int lr = l & 15, lg = l >> 4;
    const int nwg = gridDim.x;
    const int cpx = nwg >> 3;
    const int swz = (blockIdx.x & 7) * cpx + (blockIdx.x >> 3);
    const int nbx = N >> 7;
    const int bx = swz % nbx, by = swz / nbx;
    const int mBase = by * 128, nBase = bx * 128;
    const int srow = tid >> 3;
    const int skof = (tid & 7) * 8;

    f32x4 acc[4][4] = {};

    #pragma unroll
    for (int i = 0; i < 4; ++i) {
        GLOAD16(A  + (size_t)(mBase + i*32 + srow) * K + skof, &sA[0][i*2048 + w*512]);
        GLOAD16(Bm + (size_t)(nBase + i*32 + srow) * K + skof, &sB[0][i*2048 + w*512]);
    }
    int cur = 0;

    for (int kt = 0; kt < K; kt += 64) {
        __syncthreads();
        if (kt + 64 < K) {
            #pragma unroll
            for (int i = 0; i < 4; ++i) {
                GLOAD16(A  + (size_t)(mBase + i*32 + srow) * K + kt + 64 + skof, &sA[cur^1][i*2048 + w*512]);
                GLOAD16(Bm + (size_t)(nBase + i*32 + srow) * K + kt + 64 + skof, &sB[cur^1][i*2048 + w*512]);
            }
        }
        #pragma unroll
        for (int kk = 0; kk < 2; ++kk) {
            bf16x8 af[4], bfv[4];
            #pragma unroll
            for (int mi = 0; mi < 4; ++mi)
                af[mi] = *(const bf16x8*)&sA[cur][(wm*64 + mi*16 + lr)*64 + kk*32 + lg*8];
            #pragma unroll
            for (int ni = 0; ni < 4; ++ni)
                bfv[ni] = *(const bf16x8*)&sB[cur][(wn*64 + ni*16 + lr)*64 + kk*32 + lg*8];
            #pragma unroll
            for (int mi = 0; mi < 4; ++mi)
                #pragma unroll
                for (int ni = 0; ni < 4; ++ni)
                    acc[mi][ni] = __builtin_amdgcn_mfma_f32_16x16x32_bf16(af[mi], bfv[ni], acc[mi][ni], 0, 0, 0);
        }
        cur ^= 1;
    }
    #pragma unroll
    for (int mi = 0; mi < 4; ++mi) {
        #pragma unroll
        for (int j = 0; j < 4; ++j) {
            int row = mBase + wm*64 + mi*16 + lg*4 + j;
            #pragma unroll
            for (int ni = 0; ni < 4; ++ni) {
                int col = nBase + wn*64 + ni*16 + lr;
                Cout[(size_t)row * N + col] = acc[mi][ni][j] + bias[col];
            }
        }
    }
}

// ---------------------------------------------------------------- V transpose via chunk-swizzled LDS tile
// Vr [4096][1024] -> Vt [32*64][2048]
__global__ __launch_bounds__(256) void v_transpose(
    const unsigned short* __restrict__ Vr, unsigned short* __restrict__ Vt)
{
    __shared__ __align__(16) unsigned short sT[64 * 64];
    const int bh = blockIdx.y;          // 0..31
    const int st = blockIdx.x;          // 0..31 (s-tile)
    const int b = bh >> 4, h = bh & 15;
    const int tid = threadIdx.x;
    #pragma unroll
    for (int i = 0; i < 2; ++i) {
        int c = tid + i*256;            // chunk 0..511
        int s = c >> 3, cb = c & 7;
        const unsigned short* src = Vr + (size_t)(b*SS + st*64 + s) * DD + h*64 + cb*8;
        uint4 v = *(const uint4*)src;
        *(uint4*)&sT[s*64 + ((cb ^ (s >> 3)) * 8)] = v;   // chunk-swizzled store
    }
    __syncthreads();
    #pragma unroll
    for (int i = 0; i < 2; ++i) {
        int c = tid + i*256;
        int d = c >> 3, sb = c & 7;
        union { unsigned short u[8]; uint4 v; } o;
        #pragma unroll
        for (int e = 0; e < 8; ++e) {
            int s = sb*8 + e;
            o.u[e] = sT[s*64 + (((d >> 3) ^ (s >> 3)) * 8) + (d & 7)];
        }
        *(uint4*)(Vt + (size_t)(bh*64 + d) * SS + st*64 + sb*8) = o.v;
    }
}

// ---------------------------------------------------------------- flash attention fwd (causal)
// T12 structure (unchanged from R10/R11): 32x32x16 swapped-operand MFMA, in-register softmax.
__global__ __launch_bounds__(128, 2) void attn_fwd(
    const unsigned short* __restrict__ Qb,   // [4096][1024], pre-scaled by 0.125*log2e
    const unsigned short* __restrict__ Kb,   // [4096][1024]
    const unsigned short* __restrict__ Vt,   // [2048][2048]
    unsigned short* __restrict__ Ob)         // [4096][1024]
{
    __shared__ __align__(16) unsigned short sK[2][64 * 64];
    __shared__ __align__(16) unsigned short sV[2][64 * 64];
    const int tid = threadIdx.x;
    const int w = tid >> 6, l = tid & 63;
    const int lq = l & 31;
    const int hi5 = l >> 5;
    const bool hb = hi5 != 0;

    const int xcd = blockIdx.x & 7;
    const int c   = blockIdx.x >> 3;         // 0..127
    const int g   = c >> 5;                  // 0..3
    const int s_  = c & 31;                  // 0..31
    const int qt  = (g & 1) ? (31 - s_) : s_;
    const int bh  = xcd * 4 + g;
    const int b = bh >> 4, h = bh & 15;

    const int srow2 = tid >> 3;              // 0..15
    const int skof  = (tid & 7) * 8;
    const int sksw  = skof ^ ((srow2 & 7) * 8);  // pre-swizzled staging col (elements)
    const int sw    = (lq & 7) * 8;              // read-side XOR term
    const float THR = 12.0f;

    const unsigned kR = (unsigned)((b*SS + srow2) * DD + h*64 + sksw);
    const unsigned vR = (unsigned)((bh*64 + srow2) * SS + sksw);

    // Q fragments: Q[q=lq][dk = dkc*16 + hi5*8 + e]
    bf16x8 qf[4];
    {
        const unsigned short* qp = Qb + (size_t)(b*SS + qt*64 + w*32 + lq) * DD + h*64 + hi5*8;
        #pragma unroll
        for (int dkc = 0; dkc < 4; ++dkc)
            qf[dkc] = *(const bf16x8*)(qp + dkc*16);
    }
    const int q_lane = qt*64 + w*32 + lq;

    f32x16 o0 = {}, o1 = {};
    float mrow = -3.0e38f, lsum = 0.f;
    int cur = 0;

    #pragma unroll
    for (int i = 0; i < 4; ++i) {
        GLOAD16(Kb + kR + (unsigned)(i << 14), &sK[0][i*1024 + w*512]);
        GLOAD16(Vt + vR + (unsigned)(i << 15), &sV[0][i*1024 + w*512]);
    }

    for (int kt = 0; kt <= qt; ++kt) {
        __syncthreads();
        if (kt < qt) {
            unsigned ko = (unsigned)(kt + 1) << 16;
            unsigned vo = (unsigned)(kt + 1) << 6;
            #pragma unroll
            for (int i = 0; i < 4; ++i) {
                GLOAD16(Kb + kR + ko + (unsigned)(i << 14), &sK[cur^1][i*1024 + w*512]);
                GLOAD16(Vt + vR + vo + (unsigned)(i << 15), &sV[cur^1][i*1024 + w*512]);
            }
        }

        f32x16 p0 = {}, p1 = {};
        __builtin_amdgcn_s_setprio(1);
        #pragma unroll
        for (int dkc = 0; dkc < 4; ++dkc) {
            bf16x8 k0 = *(const bf16x8*)&sK[cur][lq*64 + ((dkc*16 + hi5*8) ^ sw)];
            p0 = __builtin_amdgcn_mfma_f32_32x32x16_bf16(k0, qf[dkc], p0, 0, 0, 0);
        }
        #pragma unroll
        for (int dkc = 0; dkc < 4; ++dkc) {
            bf16x8 k1 = *(const bf16x8*)&sK[cur][(32 + lq)*64 + ((dkc*16 + hi5*8) ^ sw)];
            p1 = __builtin_amdgcn_mfma_f32_32x32x16_bf16(k1, qf[dkc], p1, 0, 0, 0);
        }
        __builtin_amdgcn_s_setprio(0);

        if (kt == qt) {
            const int kb0 = kt*64 + 4*hi5;
            #pragma unroll
            for (int r = 0; r < 16; ++r) {
                const int cr = (r & 3) + 8*(r >> 2);
                if (kb0 + cr > q_lane)      p0[r] = -1e30f;
                if (kb0 + 32 + cr > q_lane) p1[r] = -1e30f;
            }
        }

        float tt[16];
        #pragma unroll
        for (int r = 0; r < 16; ++r) tt[r] = fmaxf(p0[r], p1[r]);
        #pragma unroll
        for (int s2 = 8; s2 >= 1; s2 >>= 1)
            #pragma unroll
            for (int r = 0; r < 8; ++r)
                if (r < s2) tt[r] = fmaxf(tt[r], tt[r + s2]);
        float tmx = fmaxf(tt[0], swap_half(tt[0], hb));

        float growth = tmx - mrow;
        if (!__all(growth <= THR)) {
            float mnew = fmaxf(mrow, tmx);
            float alpha = exp2f(mrow - mnew);
            lsum *= alpha;
            mrow = mnew;
            #pragma unroll
            for (int r = 0; r < 16; ++r) { o0[r] *= alpha; o1[r] *= alpha; }
        }

        #pragma unroll
        for (int r = 0; r < 16; ++r) {
            p0[r] = exp2f(p0[r] - mrow);
            p1[r] = exp2f(p1[r] - mrow);
        }
        float st[16];
        #pragma unroll
        for (int r = 0; r < 16; ++r) st[r] = p0[r] + p1[r];
        #pragma unroll
        for (int s2 = 8; s2 >= 1; s2 >>= 1)
            #pragma unroll
            for (int r = 0; r < 8; ++r)
                if (r < s2) st[r] += st[r + s2];
        lsum += st[0];

        __builtin_amdgcn_s_setprio(1);
        {
            bf16x8 pa, vf;
            pa = cvt_chunk<0>(p0);   // k 0..15
            vf = *(const bf16x8*)&sV[cur][lq*64 + ((0*16 + hi5*8) ^ sw)];
            o0 = __builtin_amdgcn_mfma_f32_32x32x16_bf16(vf, pa, o0, 0, 0, 0);
            vf = *(const bf16x8*)&sV[cur][(32 + lq)*64 + ((0*16 + hi5*8) ^ sw)];
            o1 = __builtin_amdgcn_mfma_f32_32x32x16_bf16(vf, pa, o1, 0, 0, 0);
            pa = cvt_chunk<8>(p0);   // k 16..31
            vf = *(const bf16x8*)&sV[cur][lq*64 + ((1*16 + hi5*8) ^ sw)];
            o0 = __builtin_amdgcn_mfma_f32_32x32x16_bf16(vf, pa, o0, 0, 0, 0);
            vf = *(const bf16x8*)&sV[cur][(32 + lq)*64 + ((1*16 + hi5*8) ^ sw)];
            o1 = __builtin_amdgcn_mfma_f32_32x32x16_bf16(vf, pa, o1, 0, 0, 0);
            pa = cvt_chunk<0>(p1);   // k 32..47
            vf = *(const bf16x8*)&sV[cur][lq*64 + ((2*16 + hi5*8) ^ sw)];
            o0 = __builtin_amdgcn_mfma_f32_32x32x16_bf16(vf, pa, o0, 0, 0, 0);
            vf = *(const bf16x8*)&sV[cur][(32 + lq)*64 + ((2*16 + hi5*8) ^ sw)];
            o1 = __builtin_amdgcn_mfma_f32_32x32x16_bf16(vf, pa, o1, 0, 0, 0);
            pa = cvt_chunk<8>(p1);   // k 48..63
            vf = *(const bf16x8*)&sV[cur][lq*64 + ((3*16 + hi5*8) ^ sw)];
            o0 = __builtin_amdgcn_mfma_f32_32x32x16_bf16(vf, pa, o0, 0, 0, 0);
            vf = *(const bf16x8*)&sV[cur][(32 + lq)*64 + ((3*16 + hi5*8) ^ sw)];
            o1 = __builtin_amdgcn_mfma_f32_32x32x16_bf16(vf, pa, o1, 0, 0, 0);
        }
        __builtin_amdgcn_s_setprio(0);
        cur ^= 1;
    }

    // ---- epilogue: normalize, LDS-transpose O (reuse sK), coalesced store
    __syncthreads();
    float ls = lsum + swap_half(lsum, hb);
    float inv = 1.f / ls;
    unsigned short* sO = &sK[0][0] + w * 2048;   // per-wave [32 q][64 d] bf16

    #pragma unroll
    for (int g2 = 0; g2 < 4; ++g2) {
        unsigned ua, ub; uint2 t2;
        float v0 = o0[g2*4+0]*inv, v1 = o0[g2*4+1]*inv, v2 = o0[g2*4+2]*inv, v3 = o0[g2*4+3]*inv;
        asm("v_cvt_pk_bf16_f32 %0, %1, %2" : "=v"(ua) : "v"(v0), "v"(v1));
        asm("v_cvt_pk_bf16_f32 %0, %1, %2" : "=v"(ub) : "v"(v2), "v"(v3));
        t2.x = ua; t2.y = ub;
        *(uint2*)&sO[lq*64 + g2*8 + hi5*4] = t2;
        float w0 = o1[g2*4+0]*inv, w1 = o1[g2*4+1]*inv, w2 = o1[g2*4+2]*inv, w3 = o1[g2*4+3]*inv;
        asm("v_cvt_pk_bf16_f32 %0, %1, %2" : "=v"(ua) : "v"(w0), "v"(w1));
        asm("v_cvt_pk_bf16_f32 %0, %1, %2" : "=v"(ub) : "v"(w2), "v"(w3));
        t2.x = ua; t2.y = ub;
        *(uint2*)&sO[lq*64 + 32 + g2*8 + hi5*4] = t2;
    }
    asm volatile("s_waitcnt lgkmcnt(0)" ::: "memory");
    __builtin_amdgcn_sched_barrier(0);

    const int row = l >> 1, cb2 = (l & 1) * 32;
    const unsigned short* sOr = sO + row*64 + cb2;
    unsigned short* gp = Ob + (size_t)(b*SS + qt*64 + w*32 + row) * DD + h*64 + cb2;
    #pragma unroll
    for (int c2 = 0; c2 < 4; ++c2)
        *(uint4*)(gp + c2*8) = *(const uint4*)(sOr + c2*8);
}

// ---------------------------------------------------------------- launch
extern "C" void kernel_launch(void* const* d_in, const int* in_sizes, int n_in,
                              void* d_out, int out_size, void* d_ws, size_t ws_size,
                              hipStream_t stream)
{
    const float* x  = (const float*)d_in[0];
    // d_in[1] = mask (causal tril; implemented analytically)
    const int* pids = (const int*)d_in[2];
    const float* wq = (const float*)d_in[3];
    const float* wk = (const float*)d_in[4];
    const float* wv = (const float*)d_in[5];
    const float* wo = (const float*)d_in[6];
    const float* bo = (const float*)d_in[7];
    float* out = (float*)d_out;

    char* ws = (char*)d_ws;
    unsigned short* xb   = (unsigned short*)(ws);                        // 8 MB
    unsigned short* wqkv = (unsigned short*)(ws + (size_t)( 8u<<20));    // 6 MB
    unsigned short* wob  = (unsigned short*)(ws + (size_t)(14u<<20));    // 2 MB
    unsigned short* Vr   = (unsigned short*)(ws + (size_t)(16u<<20));    // 8 MB
    unsigned short* Qb   = (unsigned short*)(ws + (size_t)(40u<<20));    // 8 MB
    unsigned short* Kb   = (unsigned short*)(ws + (size_t)(48u<<20));    // 8 MB
    unsigned short* Vt   = (unsigned short*)(ws + (size_t)(56u<<20));    // 8 MB
    float* tabc          = (float*)(ws + (size_t)(64u<<20));             // 256 KB
    float* tabs          = (float*)(ws + (size_t)(64u<<20) + (256u<<10));// 256 KB
    unsigned short* Ob   = xb;  // alias: x_bf16 dead after QKV GEMM

    cast_all<<<dim3(4096), dim3(256), 0, stream>>>(x, wq, wk, wv, wo, xb, wqkv, wob);
    rope_table<<<dim3(256), dim3(256), 0, stream>>>(tabc, tabs);
    gemm_qkv<<<dim3(768), dim3(256), 0, stream>>>(
        xb, wqkv, pids, tabc, tabs, Qb, Kb, Vr);
    v_transpose<<<dim3(32, 32), dim3(256), 0, stream>>>(Vr, Vt);
    attn_fwd<<<dim3(1024), dim3(128), 0, stream>>>(Qb, Kb, Vt, Ob);
    gemm_bt<<<dim3(256), dim3(256), 0, stream>>>(
        Ob, wob, out, bo, MROWS, DD, DD);
}